// Round 2
// baseline (531.036 us; speedup 1.0000x reference)
//
#include <hip/hip_runtime.h>
#include <hip/hip_bf16.h>

// Problem dims (fixed)
#define BB 4
#define SS 512
#define DD 1024
#define HH 16
#define KR 64
#define HDIM 64
#define THREE_D 3072
#define M_ROWS 2048   // B*S
#define SCALE_F 0.125f   // 1/sqrt(64)
#define ALPHA_F 0.25f

// ---------------------------------------------------------------------------
// GEMM 1: qkv = x @ w_qkv + b_qkv, scatter into q/k/v [B,H,S,HD] fp32
// A: [2048,1024] fp32 row-major, W: [1024,3072] fp32 row-major
// tile 64x64, BK=16, 256 threads, 4x4 per thread
// ---------------------------------------------------------------------------
__global__ __launch_bounds__(256) void gemm_qkv_kernel(
    const float* __restrict__ X,
    const float* __restrict__ W,
    const float* __restrict__ bias,
    float* __restrict__ q_ws, float* __restrict__ k_ws, float* __restrict__ v_ws)
{
    __shared__ float As[16][68];  // As[k][m], padded stride (<=2-way conflicts, free)
    __shared__ float Bs[16][68];  // Bs[k][n]

    const int tid = threadIdx.x;
    const int tx = tid & 15;      // n-quad
    const int ty = tid >> 4;      // m-quad
    const int m0 = blockIdx.y * 64;
    const int n0 = blockIdx.x * 64;

    float acc[4][4] = {};

    for (int k0 = 0; k0 < DD; k0 += 16) {
        // A tile: 64 rows x 16 cols, one float4 per thread, store transposed As[k][m]
        {
            int row = tid >> 2;             // 0..63
            int c4  = (tid & 3) * 4;        // 0,4,8,12
            const float4 a4 = *(const float4*)(X + (size_t)(m0 + row) * DD + k0 + c4);
            As[c4 + 0][row] = a4.x;
            As[c4 + 1][row] = a4.y;
            As[c4 + 2][row] = a4.z;
            As[c4 + 3][row] = a4.w;
        }
        // B tile: 16 rows x 64 cols, one float4 per thread (coalesced)
        {
            int row = tid >> 4;             // 0..15
            int c4  = (tid & 15) * 4;       // 0..60
            const float4 b4 = *(const float4*)(W + (size_t)(k0 + row) * THREE_D + n0 + c4);
            Bs[row][c4 + 0] = b4.x;
            Bs[row][c4 + 1] = b4.y;
            Bs[row][c4 + 2] = b4.z;
            Bs[row][c4 + 3] = b4.w;
        }
        __syncthreads();
#pragma unroll
        for (int kk = 0; kk < 16; ++kk) {
            float a[4], b[4];
#pragma unroll
            for (int i = 0; i < 4; ++i) a[i] = As[kk][ty * 4 + i];
#pragma unroll
            for (int j = 0; j < 4; ++j) b[j] = Bs[kk][tx * 4 + j];
#pragma unroll
            for (int i = 0; i < 4; ++i)
#pragma unroll
                for (int j = 0; j < 4; ++j)
                    acc[i][j] += a[i] * b[j];
        }
        __syncthreads();
    }

    // epilogue: add bias, scatter to q/k/v as [B,H,S,HD]
#pragma unroll
    for (int i = 0; i < 4; ++i) {
        int m = m0 + ty * 4 + i;
        int b = m >> 9;          // /512
        int s = m & 511;
#pragma unroll
        for (int j = 0; j < 4; ++j) {
            int n = n0 + tx * 4 + j;
            float val = acc[i][j] + bias[n];
            int which = n >> 10;         // 0=q,1=k,2=v
            int rem = n & 1023;
            int h = rem >> 6;
            int hd = rem & 63;
            float* dst = (which == 0) ? q_ws : ((which == 1) ? k_ws : v_ws);
            dst[(((size_t)(b * HH + h) * SS) + s) * HDIM + hd] = val;
        }
    }
}

// ---------------------------------------------------------------------------
// Attention: one wave (64 threads) per (b,h,q).
// Phase 1: lane = route index -> score. Phase 2: lane = head dim -> output.
// ---------------------------------------------------------------------------
__global__ __launch_bounds__(64) void attn_kernel(
    const float* __restrict__ q_ws, const float* __restrict__ k_ws,
    const float* __restrict__ v_ws, const int* __restrict__ routes,
    float* __restrict__ attn_out)
{
    const int idx = blockIdx.x;          // (b*H + h)*S + q
    const int qpos = idx & (SS - 1);
    const int bh = idx >> 9;             // b*H + h
    const int h = bh & (HH - 1);
    const int b = bh >> 4;
    const int lane = threadIdx.x;

    const float* qv = q_ws + (size_t)idx * HDIM;
    const float* kb = k_ws + (size_t)bh * SS * HDIM;
    const float* vb = v_ws + (size_t)bh * SS * HDIM;

    __shared__ float qs[HDIM];
    __shared__ float wsm[KR];
    __shared__ int rs[KR];

    qs[lane] = qv[lane];
    __syncthreads();

    // ---- scores: lane handles route `lane`
    const int r = routes[qpos * KR + lane];
    const int rl = (r - 1 < 0) ? 0 : r - 1;
    const int rr = (r + 1 > SS - 1) ? SS - 1 : r + 1;
    const float* k0p = kb + (size_t)r * HDIM;
    const float* k1p = kb + (size_t)rl * HDIM;
    const float* k2p = kb + (size_t)rr * HDIM;

    float dot = 0.f;
#pragma unroll 8
    for (int d = 0; d < HDIM; ++d) {
        float kv = (1.0f - ALPHA_F) * k0p[d] + (ALPHA_F * 0.5f) * (k1p[d] + k2p[d]);
        dot += qs[d] * kv;
    }
    float score = (r > qpos) ? -1e9f : dot * SCALE_F;

    // wave64 softmax
    float mx = score;
#pragma unroll
    for (int off = 32; off > 0; off >>= 1) mx = fmaxf(mx, __shfl_xor(mx, off));
    float e = __expf(score - mx);
    float ssum = e;
#pragma unroll
    for (int off = 32; off > 0; off >>= 1) ssum += __shfl_xor(ssum, off);

    wsm[lane] = e / ssum;
    rs[lane] = r;
    __syncthreads();

    // ---- output: lane handles dim `lane`; V loads coalesced across lanes
    float o = 0.f;
#pragma unroll 4
    for (int kk = 0; kk < KR; ++kk) {
        int r2 = rs[kk];
        int l2 = (r2 - 1 < 0) ? 0 : r2 - 1;
        int r3 = (r2 + 1 > SS - 1) ? SS - 1 : r2 + 1;
        float vv = (1.0f - ALPHA_F) * vb[(size_t)r2 * HDIM + lane]
                 + (ALPHA_F * 0.5f) * (vb[(size_t)l2 * HDIM + lane] + vb[(size_t)r3 * HDIM + lane]);
        o += wsm[kk] * vv;
    }
    // out[b, q, h*64 + d]
    attn_out[((size_t)(b * SS + qpos)) * DD + h * HDIM + lane] = o;
}

// ---------------------------------------------------------------------------
// GEMM 2: out = attn @ w_out + b_out  -> fp32 [B,S,D]
// A: [2048,1024] fp32 (ws), W: [1024,1024] fp32
// ---------------------------------------------------------------------------
__global__ __launch_bounds__(256) void gemm_out_kernel(
    const float* __restrict__ A,
    const float* __restrict__ W,
    const float* __restrict__ bias,
    float* __restrict__ Cout)
{
    __shared__ float As[16][68];
    __shared__ float Bs[16][68];

    const int tid = threadIdx.x;
    const int tx = tid & 15;
    const int ty = tid >> 4;
    const int m0 = blockIdx.y * 64;
    const int n0 = blockIdx.x * 64;

    float acc[4][4] = {};

    for (int k0 = 0; k0 < DD; k0 += 16) {
        {
            int row = tid >> 2;
            int c4  = (tid & 3) * 4;
            const float4 a4 = *(const float4*)(A + (size_t)(m0 + row) * DD + k0 + c4);
            As[c4 + 0][row] = a4.x;
            As[c4 + 1][row] = a4.y;
            As[c4 + 2][row] = a4.z;
            As[c4 + 3][row] = a4.w;
        }
        {
            int row = tid >> 4;
            int c4  = (tid & 15) * 4;
            const float4 b4 = *(const float4*)(W + (size_t)(k0 + row) * DD + n0 + c4);
            Bs[row][c4 + 0] = b4.x;
            Bs[row][c4 + 1] = b4.y;
            Bs[row][c4 + 2] = b4.z;
            Bs[row][c4 + 3] = b4.w;
        }
        __syncthreads();
#pragma unroll
        for (int kk = 0; kk < 16; ++kk) {
            float a[4], b[4];
#pragma unroll
            for (int i = 0; i < 4; ++i) a[i] = As[kk][ty * 4 + i];
#pragma unroll
            for (int j = 0; j < 4; ++j) b[j] = Bs[kk][tx * 4 + j];
#pragma unroll
            for (int i = 0; i < 4; ++i)
#pragma unroll
                for (int j = 0; j < 4; ++j)
                    acc[i][j] += a[i] * b[j];
        }
        __syncthreads();
    }

#pragma unroll
    for (int i = 0; i < 4; ++i) {
        int m = m0 + ty * 4 + i;
#pragma unroll
        for (int j = 0; j < 4; ++j) {
            int n = n0 + tx * 4 + j;
            Cout[(size_t)m * DD + n] = acc[i][j] + bias[n];
        }
    }
}

// ---------------------------------------------------------------------------
extern "C" void kernel_launch(void* const* d_in, const int* in_sizes, int n_in,
                              void* d_out, int out_size, void* d_ws, size_t ws_size,
                              hipStream_t stream)
{
    const float* x     = (const float*)d_in[0];
    const float* w_qkv = (const float*)d_in[1];
    const float* b_qkv = (const float*)d_in[2];
    const float* w_out = (const float*)d_in[3];
    const float* b_out = (const float*)d_in[4];
    const int* routes  = (const int*)d_in[5];

    // workspace: q,k,v [B,H,S,HD] fp32 + attn_out [B,S,D] fp32 = 32 MB
    const size_t chunk = (size_t)BB * HH * SS * HDIM;   // 2,097,152
    float* q_ws    = (float*)d_ws;
    float* k_ws    = q_ws + chunk;
    float* v_ws    = k_ws + chunk;
    float* attn_ws = v_ws + chunk;

    dim3 g1(THREE_D / 64, M_ROWS / 64);   // (48, 32)
    gemm_qkv_kernel<<<g1, 256, 0, stream>>>(x, w_qkv, b_qkv, q_ws, k_ws, v_ws);

    attn_kernel<<<BB * HH * SS, 64, 0, stream>>>(q_ws, k_ws, v_ws, routes, attn_ws);

    dim3 g2(DD / 64, M_ROWS / 64);        // (16, 32)
    gemm_out_kernel<<<g2, 256, 0, stream>>>(attn_ws, w_out, b_out, (float*)d_out);
}

// Round 3
// 248.516 us; speedup vs baseline: 2.1368x; 2.1368x over previous
//
#include <hip/hip_runtime.h>
#include <hip/hip_bf16.h>

#define BB 4
#define SS 512
#define DD 1024
#define HH 16
#define KR 64
#define HDIM 64
#define THREE_D 3072
#define M_ROWS 2048
#define SCALE_F 0.125f

typedef __attribute__((ext_vector_type(8))) short short8;
typedef __attribute__((ext_vector_type(4))) float floatx4;

union F8 { short8 s; unsigned int u[4]; unsigned short h[8]; };

__device__ inline float bf_lo(unsigned int w){ union{unsigned int u; float f;} c; c.u = w << 16; return c.f; }
__device__ inline float bf_hi(unsigned int w){ union{unsigned int u; float f;} c; c.u = w & 0xffff0000u; return c.f; }
__device__ inline float bfu(unsigned short h){ union{unsigned int u; float f;} c; c.u = ((unsigned int)h) << 16; return c.f; }
__device__ inline unsigned short f2bf(float f){
    union{float f; unsigned int u;} c; c.f = f;
    unsigned int u = c.u;
    return (unsigned short)((u + 0x7fffu + ((u >> 16) & 1u)) >> 16);   // RNE
}

// ---------------------------------------------------------------------------
// fp32 -> bf16 bulk convert (vectorized float4)
// ---------------------------------------------------------------------------
__global__ __launch_bounds__(256) void cvt_kernel(const float* __restrict__ in,
                                                  unsigned short* __restrict__ out, int n4)
{
    int i = blockIdx.x * 256 + threadIdx.x;
    if (i < n4) {
        float4 v = ((const float4*)in)[i];
        ushort4 o;
        o.x = f2bf(v.x); o.y = f2bf(v.y); o.z = f2bf(v.z); o.w = f2bf(v.w);
        ((ushort4*)out)[i] = o;
    }
}

// ---------------------------------------------------------------------------
// MFMA bf16 GEMM: C[M,N] = A[M,1024] * B[1024,N] + bias
// 128x128 tile, BK=32, 256 thr (2x2 waves of 64x64), 16x16x32 MFMA
// EPI=1: scatter into q/k/v [B,H,S,HD] fp32.  EPI=0: plain fp32 store.
// ---------------------------------------------------------------------------
template<int EPI>
__global__ __launch_bounds__(256) void gemm_bf16_mfma(
    const unsigned short* __restrict__ A,
    const unsigned short* __restrict__ Bw,
    const float* __restrict__ bias,
    float* __restrict__ Cout,
    float* __restrict__ q_ws, float* __restrict__ k_ws, float* __restrict__ v_ws,
    int N)
{
    __shared__ __align__(16) unsigned short Alds[128 * 40];  // stride 40 (pad) = 80 B
    __shared__ unsigned int Blds[16 * 132];                  // k-pair words, stride 132 words

    const int tid  = threadIdx.x;
    const int lane = tid & 63;
    const int wid  = tid >> 6;
    const int l15  = lane & 15;
    const int quad = lane >> 4;
    const int wm   = (wid >> 1) * 64;
    const int wn   = (wid & 1) * 64;
    const int m0   = blockIdx.y * 128;
    const int n0   = blockIdx.x * 128;

    floatx4 acc[4][4];
#pragma unroll
    for (int i = 0; i < 4; ++i)
#pragma unroll
        for (int j = 0; j < 4; ++j) acc[i][j] = (floatx4){0.f, 0.f, 0.f, 0.f};

    const int arow0 = tid >> 2;     // 0..63
    const int achk  = tid & 3;      // 16B chunk of the 64B row
    const int bkp   = tid >> 4;     // k-pair 0..15
    const int bnc   = tid & 15;     // n-chunk of 8

    for (int k0 = 0; k0 < 1024; k0 += 32) {
        // stage A: 128 rows x 32 cols bf16
#pragma unroll
        for (int p = 0; p < 2; ++p) {
            int row = p * 64 + arow0;
            *(F8*)(Alds + row * 40 + achk * 8) =
                *(const F8*)(A + (size_t)(m0 + row) * 1024 + k0 + achk * 8);
        }
        // stage B pair-interleaved: word = {B[2kp][n] lo, B[2kp+1][n] hi}
        {
            const unsigned short* g0 = Bw + (size_t)(k0 + 2 * bkp) * N + n0 + bnc * 8;
            F8 u0 = *(const F8*)g0;
            F8 u1 = *(const F8*)(g0 + N);
#pragma unroll
            for (int i = 0; i < 8; ++i)
                Blds[bkp * 132 + bnc * 8 + i] =
                    (unsigned int)u0.h[i] | ((unsigned int)u1.h[i] << 16);
        }
        __syncthreads();

        F8 af[4], bf[4];
#pragma unroll
        for (int mi = 0; mi < 4; ++mi)
            af[mi] = *(const F8*)(Alds + (wm + mi * 16 + l15) * 40 + quad * 8);
#pragma unroll
        for (int ni = 0; ni < 4; ++ni) {
            int nn = wn + ni * 16 + l15;
#pragma unroll
            for (int v = 0; v < 4; ++v)
                bf[ni].u[v] = Blds[(quad * 4 + v) * 132 + nn];
        }
#pragma unroll
        for (int mi = 0; mi < 4; ++mi)
#pragma unroll
            for (int ni = 0; ni < 4; ++ni)
                acc[mi][ni] = __builtin_amdgcn_mfma_f32_16x16x32_bf16(
                    af[mi].s, bf[ni].s, acc[mi][ni], 0, 0, 0);
        __syncthreads();
    }

#pragma unroll
    for (int mi = 0; mi < 4; ++mi) {
#pragma unroll
        for (int ni = 0; ni < 4; ++ni) {
            int col = n0 + wn + ni * 16 + l15;
            float bv = bias[col];
#pragma unroll
            for (int r = 0; r < 4; ++r) {
                int row = m0 + wm + mi * 16 + quad * 4 + r;
                float val = acc[mi][ni][r] + bv;
                if (EPI == 0) {
                    Cout[(size_t)row * N + col] = val;
                } else {
                    int which = col >> 10, rem = col & 1023;
                    int h = rem >> 6, hd = rem & 63;
                    int b = row >> 9, s = row & 511;
                    float* dst = (which == 0) ? q_ws : (which == 1) ? k_ws : v_ws;
                    dst[(((size_t)(b * HH + h) * SS) + s) * HDIM + hd] = val;
                }
            }
        }
    }
}

// ---------------------------------------------------------------------------
// alpha-blend K'/V' (0.75*x[s] + 0.125*(x[s-1]+x[s+1]), clamped) -> bf16
// K2g layout [bh][512*66] (stride 66 for odd-word LDS banking), V2g [bh][512*64]
// ---------------------------------------------------------------------------
__global__ __launch_bounds__(256) void blend_kernel(
    const float* __restrict__ k_ws, const float* __restrict__ v_ws,
    unsigned short* __restrict__ K2g, unsigned short* __restrict__ V2g)
{
    int idx = blockIdx.x * 256 + threadIdx.x;    // ((bh*512)+s)*64 + d
    int d  = idx & 63;
    int s  = (idx >> 6) & 511;
    int bh = idx >> 15;
    const float* kb = k_ws + (size_t)bh * SS * HDIM;
    const float* vb = v_ws + (size_t)bh * SS * HDIM;
    int sm = s ? s - 1 : 0;
    int sp = (s < SS - 1) ? s + 1 : SS - 1;
    float kv = 0.75f * kb[s * 64 + d] + 0.125f * (kb[sm * 64 + d] + kb[sp * 64 + d]);
    float vv = 0.75f * vb[s * 64 + d] + 0.125f * (vb[sm * 64 + d] + vb[sp * 64 + d]);
    K2g[(size_t)bh * 33792 + s * 66 + d] = f2bf(kv);
    V2g[(size_t)bh * 32768 + s * 64 + d] = f2bf(vv);
}

// ---------------------------------------------------------------------------
// Routed attention, LDS-resident K'/V' (133 KB of the 160 KB pool).
// Grid: 256 blocks = (bh, qtile of 128), 512 threads = 8 waves.
// Wave handles 16 queries; lane = route for scores, lane = dim for output.
// ---------------------------------------------------------------------------
__global__ __launch_bounds__(512) void attn_kernel(
    const float* __restrict__ q_ws,
    const unsigned short* __restrict__ K2g,
    const unsigned short* __restrict__ V2g,
    const int* __restrict__ routes,
    unsigned short* __restrict__ attn_out)   // [2048][1024] bf16
{
    __shared__ __align__(16) unsigned short K2s[512 * 66];  // 67584 B
    __shared__ __align__(16) unsigned short V2s[512 * 64];  // 65536 B

    const int bh   = blockIdx.x >> 2;
    const int qt   = blockIdx.x & 3;
    const int h    = bh & 15, b = bh >> 4;
    const int tid  = threadIdx.x;
    const int lane = tid & 63;
    const int wid  = tid >> 6;

    {
        const uint4* srcK = (const uint4*)(K2g + (size_t)bh * 33792);
        uint4* dstK = (uint4*)K2s;
        for (int c = tid; c < 4224; c += 512) dstK[c] = srcK[c];
        const uint4* srcV = (const uint4*)(V2g + (size_t)bh * 32768);
        uint4* dstV = (uint4*)V2s;
        for (int c = tid; c < 4096; c += 512) dstV[c] = srcV[c];
    }
    __syncthreads();

    for (int qi = 0; qi < 16; ++qi) {
        const int qpos = qt * 128 + wid * 16 + qi;
        const int r  = routes[qpos * KR + lane];
        const float qf = q_ws[((size_t)bh * SS + qpos) * HDIM + lane];

        // scores: lane's route; K row from LDS (odd word stride -> conflict-free)
        float dot = 0.f;
        const unsigned short* krow = K2s + r * 66;
#pragma unroll 8
        for (int j = 0; j < 32; ++j) {
            unsigned int w = *(const unsigned int*)(krow + 2 * j);
            float q0 = __shfl(qf, 2 * j);
            float q1 = __shfl(qf, 2 * j + 1);
            dot += q0 * bf_lo(w) + q1 * bf_hi(w);
        }
        float score = (r > qpos) ? -1e9f : dot * SCALE_F;

        float mx = score;
#pragma unroll
        for (int off = 32; off > 0; off >>= 1) mx = fmaxf(mx, __shfl_xor(mx, off));
        float e = __expf(score - mx);
        float ssum = e;
#pragma unroll
        for (int off = 32; off > 0; off >>= 1) ssum += __shfl_xor(ssum, off);
        float p = e / ssum;

        // output: lane = dim; V row broadcast across lanes (bank-minimal)
        float o = 0.f;
#pragma unroll 8
        for (int kk = 0; kk < 64; ++kk) {
            int   rk = __shfl(r, kk);
            float pw = __shfl(p, kk);
            o += pw * bfu(V2s[rk * 64 + lane]);
        }
        attn_out[(size_t)(b * SS + qpos) * DD + h * HDIM + lane] = f2bf(o);
    }
}

// ---------------------------------------------------------------------------
extern "C" void kernel_launch(void* const* d_in, const int* in_sizes, int n_in,
                              void* d_out, int out_size, void* d_ws, size_t ws_size,
                              hipStream_t stream)
{
    const float* x     = (const float*)d_in[0];
    const float* w_qkv = (const float*)d_in[1];
    const float* b_qkv = (const float*)d_in[2];
    const float* w_out = (const float*)d_in[3];
    const float* b_out = (const float*)d_in[4];
    const int* routes  = (const int*)d_in[5];

    char* w = (char*)d_ws;
    unsigned short* xb    = (unsigned short*)(w);                      // 4 MB
    unsigned short* wb1   = (unsigned short*)(w + (4u  << 20));        // 6 MB
    unsigned short* wb2   = (unsigned short*)(w + (10u << 20));        // 2 MB
    float*          q_ws  = (float*)(w + (12u << 20));                 // 8 MB
    float*          k_ws  = (float*)(w + (20u << 20));                 // 8 MB
    float*          v_ws  = (float*)(w + (28u << 20));                 // 8 MB
    unsigned short* K2g   = (unsigned short*)(w + (36u << 20));        // 4.2 MB
    unsigned short* V2g   = (unsigned short*)(w + (41u << 20));        // 4 MB
    unsigned short* attnb = (unsigned short*)(w + (45u << 20));        // 4 MB

    // bf16 conversions
    cvt_kernel<<<(M_ROWS * DD / 4 + 255) / 256, 256, 0, stream>>>(x, xb, M_ROWS * DD / 4);
    cvt_kernel<<<(DD * THREE_D / 4 + 255) / 256, 256, 0, stream>>>(w_qkv, wb1, DD * THREE_D / 4);
    cvt_kernel<<<(DD * DD / 4 + 255) / 256, 256, 0, stream>>>(w_out, wb2, DD * DD / 4);

    // QKV projection (MFMA) with scatter epilogue
    gemm_bf16_mfma<1><<<dim3(THREE_D / 128, M_ROWS / 128), 256, 0, stream>>>(
        xb, wb1, b_qkv, nullptr, q_ws, k_ws, v_ws, THREE_D);

    // neighbor blend -> bf16 K'/V'
    blend_kernel<<<(64 * SS * HDIM) / 256, 256, 0, stream>>>(k_ws, v_ws, K2g, V2g);

    // LDS-resident routed attention
    attn_kernel<<<256, 512, 0, stream>>>(q_ws, K2g, V2g, routes, attnb);

    // output projection (MFMA)
    gemm_bf16_mfma<0><<<dim3(DD / 128, M_ROWS / 128), 256, 0, stream>>>(
        attnb, wb2, b_out, (float*)d_out, nullptr, nullptr, nullptr, DD);
}

// Round 4
// 186.925 us; speedup vs baseline: 2.8409x; 1.3295x over previous
//
#include <hip/hip_runtime.h>
#include <hip/hip_bf16.h>

#define BB 4
#define SS 512
#define DD 1024
#define HH 16
#define KR 64
#define HDIM 64
#define THREE_D 3072
#define M_ROWS 2048
#define SCALE_F 0.125f

typedef __attribute__((ext_vector_type(8))) short short8;
typedef __attribute__((ext_vector_type(4))) float floatx4;

union F8 { short8 s; unsigned int u[4]; unsigned short h[8]; };

__device__ inline unsigned short f2bf(float f){
    union{float f; unsigned int u;} c; c.f = f;
    unsigned int u = c.u;
    return (unsigned short)((u + 0x7fffu + ((u >> 16) & 1u)) >> 16);   // RNE
}

// ---------------------------------------------------------------------------
// fp32 -> bf16 bulk convert (vectorized float4)
// ---------------------------------------------------------------------------
__global__ __launch_bounds__(256) void cvt_kernel(const float* __restrict__ in,
                                                  unsigned short* __restrict__ out, int n4)
{
    int i = blockIdx.x * 256 + threadIdx.x;
    if (i < n4) {
        float4 v = ((const float4*)in)[i];
        ushort4 o;
        o.x = f2bf(v.x); o.y = f2bf(v.y); o.z = f2bf(v.z); o.w = f2bf(v.w);
        ((ushort4*)out)[i] = o;
    }
}

// ---------------------------------------------------------------------------
// MFMA bf16 GEMM: C[M,N] = A[M,1024] * B[1024,N] + bias
// 128x128 tile, BK=32, 256 thr (2x2 waves of 64x64), 16x16x32 MFMA
// EPI=1: scatter into qb (bf16) / k_ws,v_ws (fp32).  EPI=0: plain fp32 store.
// ---------------------------------------------------------------------------
template<int EPI>
__global__ __launch_bounds__(256) void gemm_bf16_mfma(
    const unsigned short* __restrict__ A,
    const unsigned short* __restrict__ Bw,
    const float* __restrict__ bias,
    float* __restrict__ Cout,
    unsigned short* __restrict__ qb, float* __restrict__ k_ws, float* __restrict__ v_ws,
    int N)
{
    __shared__ __align__(16) unsigned short Alds[128 * 40];
    __shared__ unsigned int Blds[16 * 132];

    const int tid  = threadIdx.x;
    const int lane = tid & 63;
    const int wid  = tid >> 6;
    const int l15  = lane & 15;
    const int quad = lane >> 4;
    const int wm   = (wid >> 1) * 64;
    const int wn   = (wid & 1) * 64;
    const int m0   = blockIdx.y * 128;
    const int n0   = blockIdx.x * 128;

    floatx4 acc[4][4];
#pragma unroll
    for (int i = 0; i < 4; ++i)
#pragma unroll
        for (int j = 0; j < 4; ++j) acc[i][j] = (floatx4){0.f, 0.f, 0.f, 0.f};

    const int arow0 = tid >> 2;
    const int achk  = tid & 3;
    const int bkp   = tid >> 4;
    const int bnc   = tid & 15;

    for (int k0 = 0; k0 < 1024; k0 += 32) {
#pragma unroll
        for (int p = 0; p < 2; ++p) {
            int row = p * 64 + arow0;
            *(F8*)(Alds + row * 40 + achk * 8) =
                *(const F8*)(A + (size_t)(m0 + row) * 1024 + k0 + achk * 8);
        }
        {
            const unsigned short* g0 = Bw + (size_t)(k0 + 2 * bkp) * N + n0 + bnc * 8;
            F8 u0 = *(const F8*)g0;
            F8 u1 = *(const F8*)(g0 + N);
#pragma unroll
            for (int i = 0; i < 8; ++i)
                Blds[bkp * 132 + bnc * 8 + i] =
                    (unsigned int)u0.h[i] | ((unsigned int)u1.h[i] << 16);
        }
        __syncthreads();

        F8 af[4], bf[4];
#pragma unroll
        for (int mi = 0; mi < 4; ++mi)
            af[mi] = *(const F8*)(Alds + (wm + mi * 16 + l15) * 40 + quad * 8);
#pragma unroll
        for (int ni = 0; ni < 4; ++ni) {
            int nn = wn + ni * 16 + l15;
#pragma unroll
            for (int v = 0; v < 4; ++v)
                bf[ni].u[v] = Blds[(quad * 4 + v) * 132 + nn];
        }
#pragma unroll
        for (int mi = 0; mi < 4; ++mi)
#pragma unroll
            for (int ni = 0; ni < 4; ++ni)
                acc[mi][ni] = __builtin_amdgcn_mfma_f32_16x16x32_bf16(
                    af[mi].s, bf[ni].s, acc[mi][ni], 0, 0, 0);
        __syncthreads();
    }

#pragma unroll
    for (int mi = 0; mi < 4; ++mi) {
#pragma unroll
        for (int ni = 0; ni < 4; ++ni) {
            int col = n0 + wn + ni * 16 + l15;
            float bv = bias[col];
#pragma unroll
            for (int r = 0; r < 4; ++r) {
                int row = m0 + wm + mi * 16 + quad * 4 + r;
                float val = acc[mi][ni][r] + bv;
                if (EPI == 0) {
                    Cout[(size_t)row * N + col] = val;
                } else {
                    int which = col >> 10, rem = col & 1023;
                    int h = rem >> 6, hd = rem & 63;
                    int b = row >> 9, s = row & 511;
                    size_t off = (((size_t)(b * HH + h) * SS) + s) * HDIM + hd;
                    if (which == 0)      qb[off]   = f2bf(val);
                    else if (which == 1) k_ws[off] = val;
                    else                 v_ws[off] = val;
                }
            }
        }
    }
}

// ---------------------------------------------------------------------------
// blend + transpose: K'[s][d] row-major bf16, V't[d][s] bf16 (per bh)
// block = (bh, 128-s range); LDS tile with +-1 halo
// ---------------------------------------------------------------------------
__global__ __launch_bounds__(256) void blend_tr_kernel(
    const float* __restrict__ k_ws, const float* __restrict__ v_ws,
    unsigned short* __restrict__ K2g, unsigned short* __restrict__ Vtg)
{
    __shared__ float kt[130][65];
    __shared__ float vt[130][65];
    const int bh = blockIdx.x >> 2;
    const int sb = (blockIdx.x & 3) * 128;
    const int tid = threadIdx.x;
    const float* kbase = k_ws + (size_t)bh * SS * HDIM;
    const float* vbase = v_ws + (size_t)bh * SS * HDIM;

    for (int i = tid; i < 130 * 16; i += 256) {
        int row = i >> 4, c4 = (i & 15) << 2;
        int s = sb + row - 1; s = s < 0 ? 0 : (s > SS - 1 ? SS - 1 : s);
        float4 kk = *(const float4*)(kbase + (size_t)s * 64 + c4);
        float4 vv = *(const float4*)(vbase + (size_t)s * 64 + c4);
        kt[row][c4] = kk.x; kt[row][c4+1] = kk.y; kt[row][c4+2] = kk.z; kt[row][c4+3] = kk.w;
        vt[row][c4] = vv.x; vt[row][c4+1] = vv.y; vt[row][c4+2] = vv.z; vt[row][c4+3] = vv.w;
    }
    __syncthreads();

    // K' row-major
    for (int i = tid; i < 128 * 16; i += 256) {
        int sl = i >> 4, c4 = (i & 15) << 2;
        ushort4 o;
        float v0 = 0.75f * kt[sl+1][c4+0] + 0.125f * (kt[sl][c4+0] + kt[sl+2][c4+0]);
        float v1 = 0.75f * kt[sl+1][c4+1] + 0.125f * (kt[sl][c4+1] + kt[sl+2][c4+1]);
        float v2 = 0.75f * kt[sl+1][c4+2] + 0.125f * (kt[sl][c4+2] + kt[sl+2][c4+2]);
        float v3 = 0.75f * kt[sl+1][c4+3] + 0.125f * (kt[sl][c4+3] + kt[sl+2][c4+3]);
        o.x = f2bf(v0); o.y = f2bf(v1); o.z = f2bf(v2); o.w = f2bf(v3);
        *(ushort4*)(K2g + ((size_t)bh * SS + sb + sl) * 64 + c4) = o;
    }
    // V' transposed
    for (int i = tid; i < 64 * 32; i += 256) {
        int d = i >> 5, s4 = (i & 31) << 2;
        ushort4 o;
        float v0 = 0.75f * vt[s4+1][d] + 0.125f * (vt[s4+0][d] + vt[s4+2][d]);
        float v1 = 0.75f * vt[s4+2][d] + 0.125f * (vt[s4+1][d] + vt[s4+3][d]);
        float v2 = 0.75f * vt[s4+3][d] + 0.125f * (vt[s4+2][d] + vt[s4+4][d]);
        float v3 = 0.75f * vt[s4+4][d] + 0.125f * (vt[s4+3][d] + vt[s4+5][d]);
        o.x = f2bf(v0); o.y = f2bf(v1); o.z = f2bf(v2); o.w = f2bf(v3);
        *(ushort4*)(Vtg + ((size_t)bh * 64 + d) * SS + sb + s4) = o;
    }
}

// ---------------------------------------------------------------------------
// mask bitmap: maskg[sw][q] bit s&31 set iff (s in routes[q]) && (s <= q)
// ---------------------------------------------------------------------------
__global__ __launch_bounds__(256) void mask_kernel(const int* __restrict__ routes,
                                                   unsigned int* __restrict__ maskg)
{
    int q = blockIdx.x * 256 + threadIdx.x;
    unsigned int w[16];
#pragma unroll
    for (int i = 0; i < 16; ++i) w[i] = 0u;
    for (int j = 0; j < KR; ++j) {
        int r = routes[q * KR + j];
        if (r <= q) w[r >> 5] |= 1u << (r & 31);
    }
#pragma unroll
    for (int sw = 0; sw < 16; ++sw) maskg[sw * SS + q] = w[sw];
}

// ---------------------------------------------------------------------------
// Dense masked flash attention via MFMA.
// Block = (bh, 128-q tile), 512 thr = 8 waves, wave = 16 queries.
// S^T = K'.Q^T (q in lane-cols -> lane-local softmax stats),
// mask+scale+exp, P -> per-wave swizzled LDS, O = P.V't.
// ---------------------------------------------------------------------------
__global__ __launch_bounds__(512, 2) void attn_kernel(
    const unsigned short* __restrict__ qb,    // [64][512][64] bf16
    const unsigned short* __restrict__ K2g,   // [64][512][64] bf16
    const unsigned short* __restrict__ Vtg,   // [64][64][512] bf16
    const unsigned int* __restrict__ maskg,   // [16][512]
    unsigned short* __restrict__ attn_out)    // [2048][1024] bf16
{
    __shared__ __align__(16) unsigned short Ks[512 * 64];  // swizzled 16B chunks
    __shared__ __align__(16) unsigned short Vs[64 * 512];  // swizzled 16B chunks
    __shared__ __align__(16) unsigned short Ps[8 * 16 * 64];

    const int bh = blockIdx.x >> 2;
    const int qt = blockIdx.x & 3;
    const int b = bh >> 4, h = bh & 15;
    const int tid  = threadIdx.x;
    const int lane = tid & 63;
    const int wid  = tid >> 6;
    const int l15  = lane & 15;
    const int quad = lane >> 4;

    // ---- stage K' and V't (XOR-swizzled chunk layouts)
    {
        const uint4* src = (const uint4*)(K2g + (size_t)bh * (SS * 64));
        uint4* dst = (uint4*)Ks;
        for (int c = tid; c < 4096; c += 512) {
            int s = c >> 3, cc = c & 7;
            dst[(s << 3) | (cc ^ (s & 7))] = src[c];
        }
        const uint4* srcv = (const uint4*)(Vtg + (size_t)bh * (64 * SS));
        uint4* dstv = (uint4*)Vs;
        for (int c = tid; c < 4096; c += 512) {
            int d = c >> 6, sc = c & 63;
            dstv[(d << 6) | (sc & 56) | ((sc ^ d) & 7)] = srcv[c];
        }
    }
    __syncthreads();

    const int qbase = qt * 128 + wid * 16;
    const int q = qbase + l15;    // this lane's column

    // Q B-frags (n=q, k=d), 2 k-steps, straight from global bf16
    F8 qf[2];
    {
        const unsigned short* qrow = qb + ((size_t)bh * SS + q) * 64;
        qf[0] = *(const F8*)(qrow + quad * 8);
        qf[1] = *(const F8*)(qrow + 32 + quad * 8);
    }

    // ---- S^T phase: 32 s-tiles of 16
    floatx4 accS[32];
#pragma unroll
    for (int st = 0; st < 32; ++st) {
        int srow = st * 16 + l15;
        const F8 k0 = *(const F8*)(Ks + (((srow << 3) | ( quad      ^ (srow & 7))) << 3));
        const F8 k1 = *(const F8*)(Ks + (((srow << 3) | ((4 + quad) ^ (srow & 7))) << 3));
        floatx4 a = (floatx4){0.f, 0.f, 0.f, 0.f};
        a = __builtin_amdgcn_mfma_f32_16x16x32_bf16(k0.s, qf[0].s, a, 0, 0, 0);
        a = __builtin_amdgcn_mfma_f32_16x16x32_bf16(k1.s, qf[1].s, a, 0, 0, 0);
        accS[st] = a;
    }

    // ---- mask + scale + row max (lane-local; q fixed per lane)
    float m = -1e30f;
    unsigned int mw = 0;
#pragma unroll
    for (int st = 0; st < 32; ++st) {
        if ((st & 1) == 0) mw = maskg[(st >> 1) * SS + q];
        int sbase = (st & 1) * 16 + quad * 4;
        floatx4 a = accS[st];
#pragma unroll
        for (int r = 0; r < 4; ++r) {
            float v = ((mw >> (sbase + r)) & 1u) ? a[r] * SCALE_F : -1e30f;
            a[r] = v;
            m = fmaxf(m, v);
        }
        accS[st] = a;
    }
    m = fmaxf(m, __shfl_xor(m, 16));
    m = fmaxf(m, __shfl_xor(m, 32));

    // ---- PV phase: 8 s-chunks of 64; exp -> P (bf16, swizzled per-wave LDS) -> MFMA
    floatx4 accO[4];
#pragma unroll
    for (int dt = 0; dt < 4; ++dt) accO[dt] = (floatx4){0.f, 0.f, 0.f, 0.f};
    float lsum = 0.f;
    unsigned int* Pw = (unsigned int*)Ps + wid * 16 * 32;   // 32 words/row

#pragma unroll
    for (int ch = 0; ch < 8; ++ch) {
#pragma unroll
        for (int t = 0; t < 4; ++t) {
            floatx4 a = accS[ch * 4 + t];
            float e0 = __expf(a[0] - m), e1 = __expf(a[1] - m);
            float e2 = __expf(a[2] - m), e3 = __expf(a[3] - m);
            lsum += (e0 + e1) + (e2 + e3);
            unsigned int w0 = (unsigned int)f2bf(e0) | ((unsigned int)f2bf(e1) << 16);
            unsigned int w1 = (unsigned int)f2bf(e2) | ((unsigned int)f2bf(e3) << 16);
            int off0 = t * 8 + quad * 2;       // word offset in row (s_off/2)
            int off1 = off0 + 1;
            Pw[l15 * 32 + ((((off0 >> 2) ^ (l15 & 7)) << 2) | (off0 & 3))] = w0;
            Pw[l15 * 32 + ((((off1 >> 2) ^ (l15 & 7)) << 2) | (off1 & 3))] = w1;
        }
        // A-frags (P) from swizzled per-wave LDS
        F8 pa[2];
#pragma unroll
        for (int ks = 0; ks < 2; ++ks) {
            int ci = ks * 4 + quad;
            pa[ks] = *(const F8*)((const unsigned short*)(Pw + l15 * 32) +
                                  (((ci ^ (l15 & 7)) << 3)));
        }
        // B-frags (V't) + MFMA
#pragma unroll
        for (int dt = 0; dt < 4; ++dt) {
            int d = dt * 16 + l15;
#pragma unroll
            for (int ks = 0; ks < 2; ++ks) {
                int sc = ch * 8 + ks * 4 + quad;
                const F8 bv = *(const F8*)(Vs + (((d << 6) | (sc & 56) | ((sc ^ d) & 7)) << 3));
                accO[dt] = __builtin_amdgcn_mfma_f32_16x16x32_bf16(pa[ks].s, bv.s, accO[dt], 0, 0, 0);
            }
        }
    }

    lsum += __shfl_xor(lsum, 16);
    lsum += __shfl_xor(lsum, 32);
    float inv = 1.0f / lsum;

    // ---- epilogue: O row q = qbase + quad*4 + r, col d = dt*16 + l15
#pragma unroll
    for (int r = 0; r < 4; ++r) {
        float invr = __shfl(inv, quad * 4 + r);
        int qrow = qbase + quad * 4 + r;
        size_t rowoff = (size_t)(b * SS + qrow) * DD + h * 64;
#pragma unroll
        for (int dt = 0; dt < 4; ++dt)
            attn_out[rowoff + dt * 16 + l15] = f2bf(accO[dt][r] * invr);
    }
}

// ---------------------------------------------------------------------------
extern "C" void kernel_launch(void* const* d_in, const int* in_sizes, int n_in,
                              void* d_out, int out_size, void* d_ws, size_t ws_size,
                              hipStream_t stream)
{
    const float* x     = (const float*)d_in[0];
    const float* w_qkv = (const float*)d_in[1];
    const float* b_qkv = (const float*)d_in[2];
    const float* w_out = (const float*)d_in[3];
    const float* b_out = (const float*)d_in[4];
    const int* routes  = (const int*)d_in[5];

    char* w = (char*)d_ws;
    unsigned short* xb    = (unsigned short*)(w);                 // 4 MB
    unsigned short* wb1   = (unsigned short*)(w + (4u  << 20));   // 6 MB
    unsigned short* wb2   = (unsigned short*)(w + (10u << 20));   // 2 MB
    unsigned short* qbuf  = (unsigned short*)(w + (12u << 20));   // 4 MB bf16
    float*          k_ws  = (float*)(w + (16u << 20));            // 8 MB
    float*          v_ws  = (float*)(w + (24u << 20));            // 8 MB
    unsigned short* K2g   = (unsigned short*)(w + (32u << 20));   // 4 MB
    unsigned short* Vtg   = (unsigned short*)(w + (36u << 20));   // 4 MB
    unsigned short* attnb = (unsigned short*)(w + (40u << 20));   // 4 MB
    unsigned int*   maskg = (unsigned int*)(w + (44u << 20));     // 32 KB

    cvt_kernel<<<(M_ROWS * DD / 4 + 255) / 256, 256, 0, stream>>>(x, xb, M_ROWS * DD / 4);
    cvt_kernel<<<(DD * THREE_D / 4 + 255) / 256, 256, 0, stream>>>(w_qkv, wb1, DD * THREE_D / 4);
    cvt_kernel<<<(DD * DD / 4 + 255) / 256, 256, 0, stream>>>(w_out, wb2, DD * DD / 4);

    mask_kernel<<<2, 256, 0, stream>>>(routes, maskg);

    gemm_bf16_mfma<1><<<dim3(THREE_D / 128, M_ROWS / 128), 256, 0, stream>>>(
        xb, wb1, b_qkv, nullptr, qbuf, k_ws, v_ws, THREE_D);

    blend_tr_kernel<<<256, 256, 0, stream>>>(k_ws, v_ws, K2g, Vtg);

    attn_kernel<<<256, 512, 0, stream>>>(qbuf, K2g, Vtg, maskg, attnb);

    gemm_bf16_mfma<0><<<dim3(DD / 128, M_ROWS / 128), 256, 0, stream>>>(
        attnb, wb2, b_out, (float*)d_out, nullptr, nullptr, nullptr, DD);
}

// Round 5
// 171.908 us; speedup vs baseline: 3.0891x; 1.0874x over previous
//
#include <hip/hip_runtime.h>
#include <hip/hip_bf16.h>

#define BB 4
#define SS 512
#define DD 1024
#define HH 16
#define KR 64
#define HDIM 64
#define THREE_D 3072
#define M_ROWS 2048
#define SCALE_F 0.125f

typedef __attribute__((ext_vector_type(8))) short short8;
typedef __attribute__((ext_vector_type(4))) float floatx4;

union F8 { short8 s; unsigned int u[4]; unsigned short h[8]; };

__device__ inline unsigned short f2bf(float f){
    union{float f; unsigned int u;} c; c.f = f;
    unsigned int u = c.u;
    return (unsigned short)((u + 0x7fffu + ((u >> 16) & 1u)) >> 16);   // RNE
}

#define GLOAD_LDS16(g, l)                                                     \
    __builtin_amdgcn_global_load_lds(                                         \
        (const __attribute__((address_space(1))) unsigned int*)(g),           \
        (__attribute__((address_space(3))) unsigned int*)(l), 16, 0, 0)

// ---------------------------------------------------------------------------
// cvt_A: x fp32 [2048][1024] -> bf16 swizzled chunks [mt][kt][c][r]
// chunk (16B, 8 elems) = rows mt*128+r, cols kt*32+c*8..+7
// ---------------------------------------------------------------------------
__global__ __launch_bounds__(256) void cvtA_kernel(const float* __restrict__ x,
                                                   unsigned short* __restrict__ out)
{
    int gid = blockIdx.x * 256 + threadIdx.x;        // 0..262143
    int r  = gid & 127;
    int c  = (gid >> 7) & 3;
    int kt = (gid >> 9) & 31;
    int mt = gid >> 14;
    const float* src = x + ((size_t)(mt * 128 + r)) * 1024 + kt * 32 + c * 8;
    float4 a = *(const float4*)src;
    float4 b = *(const float4*)(src + 4);
    F8 o;
    o.h[0] = f2bf(a.x); o.h[1] = f2bf(a.y); o.h[2] = f2bf(a.z); o.h[3] = f2bf(a.w);
    o.h[4] = f2bf(b.x); o.h[5] = f2bf(b.y); o.h[6] = f2bf(b.z); o.h[7] = f2bf(b.w);
    *(uint4*)(out + (size_t)gid * 8) = *(uint4*)&o;
}

// ---------------------------------------------------------------------------
// cvt_B: W fp32 [1024][N] -> W^T bf16 swizzled chunks [nt][kt][c][r]
// chunk = W^T row n = nt*128+r, k = kt*32+c*8..+7  (i.e. W[k][n])
// ---------------------------------------------------------------------------
__global__ __launch_bounds__(256) void cvtB_kernel(const float* __restrict__ w,
                                                   unsigned short* __restrict__ out, int N)
{
    int gid = blockIdx.x * 256 + threadIdx.x;
    int r  = gid & 127;
    int c  = (gid >> 7) & 3;
    int kt = (gid >> 9) & 31;
    int nt = gid >> 14;
    int n = nt * 128 + r;
    int kbase = kt * 32 + c * 8;
    F8 o;
#pragma unroll
    for (int j = 0; j < 8; ++j)
        o.h[j] = f2bf(w[(size_t)(kbase + j) * N + n]);
    *(uint4*)(out + (size_t)gid * 8) = *(uint4*)&o;
}

// ---------------------------------------------------------------------------
// m97-style MFMA GEMM: C[M,N] = A * B + bias, A/B pre-swizzled bf16 chunks.
// 128x128 tile, BK=32, 256 thr, global_load_lds width-16 staging.
// EPI=1: scatter into qb (bf16) / k_ws,v_ws (fp32).  EPI=0: plain fp32 store.
// ---------------------------------------------------------------------------
template<int EPI>
__global__ __launch_bounds__(256) void gemm_mfma(
    const unsigned short* __restrict__ Asw,
    const unsigned short* __restrict__ Bsw,
    const float* __restrict__ bias,
    float* __restrict__ Cout,
    unsigned short* __restrict__ qb, float* __restrict__ k_ws, float* __restrict__ v_ws,
    int N)
{
    __shared__ __align__(16) unsigned short Alds[4096];   // 8 KB, chunks [c][r]
    __shared__ __align__(16) unsigned short Blds[4096];

    const int tid  = threadIdx.x;
    const int lane = tid & 63;
    const int wid  = tid >> 6;
    const int l15  = lane & 15;
    const int quad = lane >> 4;
    const int wm   = (wid >> 1) * 64;
    const int wn   = (wid & 1) * 64;

    const unsigned short* Ak = Asw + (size_t)blockIdx.y * 131072;   // 32 kt * 4096
    const unsigned short* Bk = Bsw + (size_t)blockIdx.x * 131072;

    floatx4 acc[4][4];
#pragma unroll
    for (int i = 0; i < 4; ++i)
#pragma unroll
        for (int j = 0; j < 4; ++j) acc[i][j] = (floatx4){0.f, 0.f, 0.f, 0.f};

    for (int kt = 0; kt < 32; ++kt) {
        const unsigned short* ga = Ak + kt * 4096 + wid * 1024 + lane * 8;
        const unsigned short* gb = Bk + kt * 4096 + wid * 1024 + lane * 8;
        GLOAD_LDS16(ga,       Alds + wid * 1024);
        GLOAD_LDS16(ga + 512, Alds + wid * 1024 + 512);
        GLOAD_LDS16(gb,       Blds + wid * 1024);
        GLOAD_LDS16(gb + 512, Blds + wid * 1024 + 512);
        __syncthreads();

        F8 af[4], bf[4];
#pragma unroll
        for (int mi = 0; mi < 4; ++mi)
            af[mi] = *(const F8*)(Alds + (size_t)(quad * 128 + wm + mi * 16 + l15) * 8);
#pragma unroll
        for (int ni = 0; ni < 4; ++ni)
            bf[ni] = *(const F8*)(Blds + (size_t)(quad * 128 + wn + ni * 16 + l15) * 8);
#pragma unroll
        for (int mi = 0; mi < 4; ++mi)
#pragma unroll
            for (int ni = 0; ni < 4; ++ni)
                acc[mi][ni] = __builtin_amdgcn_mfma_f32_16x16x32_bf16(
                    af[mi].s, bf[ni].s, acc[mi][ni], 0, 0, 0);
        __syncthreads();
    }

    const int m0 = blockIdx.y * 128;
    const int n0 = blockIdx.x * 128;
#pragma unroll
    for (int mi = 0; mi < 4; ++mi) {
#pragma unroll
        for (int ni = 0; ni < 4; ++ni) {
            int col = n0 + wn + ni * 16 + l15;
            float bv = bias[col];
#pragma unroll
            for (int r = 0; r < 4; ++r) {
                int row = m0 + wm + mi * 16 + quad * 4 + r;
                float val = acc[mi][ni][r] + bv;
                if (EPI == 0) {
                    Cout[(size_t)row * N + col] = val;
                } else {
                    int which = col >> 10, rem = col & 1023;
                    int h = rem >> 6, hd = rem & 63;
                    int b = row >> 9, s = row & 511;
                    size_t off = (((size_t)(b * HH + h) * SS) + s) * HDIM + hd;
                    if (which == 0)      qb[off]   = f2bf(val);
                    else if (which == 1) k_ws[off] = val;
                    else                 v_ws[off] = val;
                }
            }
        }
    }
}

// ---------------------------------------------------------------------------
// blend + transpose: K'[s][d] row-major bf16, V't[d][s] bf16 (per bh)
// ---------------------------------------------------------------------------
__global__ __launch_bounds__(256) void blend_tr_kernel(
    const float* __restrict__ k_ws, const float* __restrict__ v_ws,
    unsigned short* __restrict__ K2g, unsigned short* __restrict__ Vtg)
{
    __shared__ float kt[130][65];
    __shared__ float vt[130][65];
    const int bh = blockIdx.x >> 2;
    const int sb = (blockIdx.x & 3) * 128;
    const int tid = threadIdx.x;
    const float* kbase = k_ws + (size_t)bh * SS * HDIM;
    const float* vbase = v_ws + (size_t)bh * SS * HDIM;

    for (int i = tid; i < 130 * 16; i += 256) {
        int row = i >> 4, c4 = (i & 15) << 2;
        int s = sb + row - 1; s = s < 0 ? 0 : (s > SS - 1 ? SS - 1 : s);
        float4 kk = *(const float4*)(kbase + (size_t)s * 64 + c4);
        float4 vv = *(const float4*)(vbase + (size_t)s * 64 + c4);
        kt[row][c4] = kk.x; kt[row][c4+1] = kk.y; kt[row][c4+2] = kk.z; kt[row][c4+3] = kk.w;
        vt[row][c4] = vv.x; vt[row][c4+1] = vv.y; vt[row][c4+2] = vv.z; vt[row][c4+3] = vv.w;
    }
    __syncthreads();

    for (int i = tid; i < 128 * 16; i += 256) {
        int sl = i >> 4, c4 = (i & 15) << 2;
        ushort4 o;
        o.x = f2bf(0.75f * kt[sl+1][c4+0] + 0.125f * (kt[sl][c4+0] + kt[sl+2][c4+0]));
        o.y = f2bf(0.75f * kt[sl+1][c4+1] + 0.125f * (kt[sl][c4+1] + kt[sl+2][c4+1]));
        o.z = f2bf(0.75f * kt[sl+1][c4+2] + 0.125f * (kt[sl][c4+2] + kt[sl+2][c4+2]));
        o.w = f2bf(0.75f * kt[sl+1][c4+3] + 0.125f * (kt[sl][c4+3] + kt[sl+2][c4+3]));
        *(ushort4*)(K2g + ((size_t)bh * SS + sb + sl) * 64 + c4) = o;
    }
    for (int i = tid; i < 64 * 32; i += 256) {
        int d = i >> 5, s4 = (i & 31) << 2;
        ushort4 o;
        o.x = f2bf(0.75f * vt[s4+1][d] + 0.125f * (vt[s4+0][d] + vt[s4+2][d]));
        o.y = f2bf(0.75f * vt[s4+2][d] + 0.125f * (vt[s4+1][d] + vt[s4+3][d]));
        o.z = f2bf(0.75f * vt[s4+3][d] + 0.125f * (vt[s4+2][d] + vt[s4+4][d]));
        o.w = f2bf(0.75f * vt[s4+4][d] + 0.125f * (vt[s4+3][d] + vt[s4+5][d]));
        *(ushort4*)(Vtg + ((size_t)bh * 64 + d) * SS + sb + s4) = o;
    }
}

// ---------------------------------------------------------------------------
__global__ __launch_bounds__(256) void mask_kernel(const int* __restrict__ routes,
                                                   unsigned int* __restrict__ maskg)
{
    int q = blockIdx.x * 256 + threadIdx.x;
    unsigned int w[16];
#pragma unroll
    for (int i = 0; i < 16; ++i) w[i] = 0u;
    for (int j = 0; j < KR; ++j) {
        int r = routes[q * KR + j];
        if (r <= q) w[r >> 5] |= 1u << (r & 31);
    }
#pragma unroll
    for (int sw = 0; sw < 16; ++sw) maskg[sw * SS + q] = w[sw];
}

// ---------------------------------------------------------------------------
// Dense masked flash attention via MFMA; output written in swizzled chunk
// layout so gemm2 can stage it with global_load_lds.
// ---------------------------------------------------------------------------
__global__ __launch_bounds__(512, 2) void attn_kernel(
    const unsigned short* __restrict__ qb,    // [64][512][64] bf16
    const unsigned short* __restrict__ K2g,   // [64][512][64] bf16
    const unsigned short* __restrict__ Vtg,   // [64][64][512] bf16
    const unsigned int* __restrict__ maskg,   // [16][512]
    unsigned short* __restrict__ attn_sw)     // swizzled chunks [mt][kt][c][r]
{
    __shared__ __align__(16) unsigned short Ks[512 * 64];
    __shared__ __align__(16) unsigned short Vs[64 * 512];
    __shared__ __align__(16) unsigned short Ps[8 * 16 * 64];

    const int bh = blockIdx.x >> 2;
    const int qt = blockIdx.x & 3;
    const int b = bh >> 4, h = bh & 15;
    const int tid  = threadIdx.x;
    const int lane = tid & 63;
    const int wid  = tid >> 6;
    const int l15  = lane & 15;
    const int quad = lane >> 4;

    {
        const uint4* src = (const uint4*)(K2g + (size_t)bh * (SS * 64));
        uint4* dst = (uint4*)Ks;
        for (int c = tid; c < 4096; c += 512) {
            int s = c >> 3, cc = c & 7;
            dst[(s << 3) | (cc ^ (s & 7))] = src[c];
        }
        const uint4* srcv = (const uint4*)(Vtg + (size_t)bh * (64 * SS));
        uint4* dstv = (uint4*)Vs;
        for (int c = tid; c < 4096; c += 512) {
            int d = c >> 6, sc = c & 63;
            dstv[(d << 6) | (sc & 56) | ((sc ^ d) & 7)] = srcv[c];
        }
    }
    __syncthreads();

    const int qbase = qt * 128 + wid * 16;
    const int q = qbase + l15;

    F8 qf[2];
    {
        const unsigned short* qrow = qb + ((size_t)bh * SS + q) * 64;
        qf[0] = *(const F8*)(qrow + quad * 8);
        qf[1] = *(const F8*)(qrow + 32 + quad * 8);
    }

    floatx4 accS[32];
#pragma unroll
    for (int st = 0; st < 32; ++st) {
        int srow = st * 16 + l15;
        const F8 k0 = *(const F8*)(Ks + (((srow << 3) | ( quad      ^ (srow & 7))) << 3));
        const F8 k1 = *(const F8*)(Ks + (((srow << 3) | ((4 + quad) ^ (srow & 7))) << 3));
        floatx4 a = (floatx4){0.f, 0.f, 0.f, 0.f};
        a = __builtin_amdgcn_mfma_f32_16x16x32_bf16(k0.s, qf[0].s, a, 0, 0, 0);
        a = __builtin_amdgcn_mfma_f32_16x16x32_bf16(k1.s, qf[1].s, a, 0, 0, 0);
        accS[st] = a;
    }

    float m = -1e30f;
    unsigned int mw = 0;
#pragma unroll
    for (int st = 0; st < 32; ++st) {
        if ((st & 1) == 0) mw = maskg[(st >> 1) * SS + q];
        int sbase = (st & 1) * 16 + quad * 4;
        floatx4 a = accS[st];
#pragma unroll
        for (int r = 0; r < 4; ++r) {
            float v = ((mw >> (sbase + r)) & 1u) ? a[r] * SCALE_F : -1e30f;
            a[r] = v;
            m = fmaxf(m, v);
        }
        accS[st] = a;
    }
    m = fmaxf(m, __shfl_xor(m, 16));
    m = fmaxf(m, __shfl_xor(m, 32));

    floatx4 accO[4];
#pragma unroll
    for (int dt = 0; dt < 4; ++dt) accO[dt] = (floatx4){0.f, 0.f, 0.f, 0.f};
    float lsum = 0.f;
    unsigned int* Pw = (unsigned int*)Ps + wid * 512;

#pragma unroll
    for (int ch = 0; ch < 8; ++ch) {
#pragma unroll
        for (int t = 0; t < 4; ++t) {
            floatx4 a = accS[ch * 4 + t];
            float e0 = __expf(a[0] - m), e1 = __expf(a[1] - m);
            float e2 = __expf(a[2] - m), e3 = __expf(a[3] - m);
            lsum += (e0 + e1) + (e2 + e3);
            unsigned int w0 = (unsigned int)f2bf(e0) | ((unsigned int)f2bf(e1) << 16);
            unsigned int w1 = (unsigned int)f2bf(e2) | ((unsigned int)f2bf(e3) << 16);
            int off0 = t * 8 + quad * 2;
            int off1 = off0 + 1;
            Pw[l15 * 32 + ((((off0 >> 2) ^ (l15 & 7)) << 2) | (off0 & 3))] = w0;
            Pw[l15 * 32 + ((((off1 >> 2) ^ (l15 & 7)) << 2) | (off1 & 3))] = w1;
        }
        F8 pa[2];
#pragma unroll
        for (int ks = 0; ks < 2; ++ks) {
            int ci = ks * 4 + quad;
            pa[ks] = *(const F8*)((const unsigned short*)(Pw + l15 * 32) +
                                  ((ci ^ (l15 & 7)) << 3));
        }
#pragma unroll
        for (int dt = 0; dt < 4; ++dt) {
            int d = dt * 16 + l15;
#pragma unroll
            for (int ks = 0; ks < 2; ++ks) {
                int sc = ch * 8 + ks * 4 + quad;
                const F8 bv = *(const F8*)(Vs + (((d << 6) | (sc & 56) | ((sc ^ d) & 7)) << 3));
                accO[dt] = __builtin_amdgcn_mfma_f32_16x16x32_bf16(pa[ks].s, bv.s, accO[dt], 0, 0, 0);
            }
        }
    }

    lsum += __shfl_xor(lsum, 16);
    lsum += __shfl_xor(lsum, 32);
    float inv = 1.0f / lsum;

    // ---- epilogue: O -> per-wave LDS -> swizzled global chunks
    unsigned short* Ow = Ps + wid * 1024;
#pragma unroll
    for (int r = 0; r < 4; ++r) {
        float invr = __shfl(inv, quad * 4 + r);
#pragma unroll
        for (int dt = 0; dt < 4; ++dt)
            Ow[(quad * 4 + r) * 64 + dt * 16 + l15] = f2bf(accO[dt][r] * invr);
    }
#pragma unroll
    for (int i = 0; i < 2; ++i) {
        int ch = i * 64 + lane;               // 0..127
        int qlocal = ch >> 3, j = ch & 7;
        int qq = qt * 128 + wid * 16 + qlocal;
        int mrow = b * SS + qq;
        int mt = mrow >> 7, rr = mrow & 127;
        int kt2 = h * 2 + (j >> 2), c = j & 3;
        size_t gid = (((size_t)(mt * 32 + kt2) * 4 + c) * 128 + rr);
        *(uint4*)(attn_sw + gid * 8) = *(const uint4*)(Ow + qlocal * 64 + j * 8);
    }
}

// ---------------------------------------------------------------------------
extern "C" void kernel_launch(void* const* d_in, const int* in_sizes, int n_in,
                              void* d_out, int out_size, void* d_ws, size_t ws_size,
                              hipStream_t stream)
{
    const float* x     = (const float*)d_in[0];
    const float* w_qkv = (const float*)d_in[1];
    const float* b_qkv = (const float*)d_in[2];
    const float* w_out = (const float*)d_in[3];
    const float* b_out = (const float*)d_in[4];
    const int* routes  = (const int*)d_in[5];

    char* w = (char*)d_ws;
    unsigned short* xb_sw  = (unsigned short*)(w);                 // 4 MB
    unsigned short* wb1_sw = (unsigned short*)(w + (4u  << 20));   // 6 MB
    unsigned short* wb2_sw = (unsigned short*)(w + (10u << 20));   // 2 MB
    unsigned short* qbuf   = (unsigned short*)(w + (12u << 20));   // 4 MB
    float*          k_ws   = (float*)(w + (16u << 20));            // 8 MB
    float*          v_ws   = (float*)(w + (24u << 20));            // 8 MB
    unsigned short* K2g    = (unsigned short*)(w + (32u << 20));   // 4 MB
    unsigned short* Vtg    = (unsigned short*)(w + (36u << 20));   // 4 MB
    unsigned short* attnsw = (unsigned short*)(w + (40u << 20));   // 4 MB
    unsigned int*   maskg  = (unsigned int*)(w + (44u << 20));     // 32 KB

    cvtA_kernel<<<1024, 256, 0, stream>>>(x, xb_sw);
    cvtB_kernel<<<1536, 256, 0, stream>>>(w_qkv, wb1_sw, THREE_D);
    cvtB_kernel<<<512, 256, 0, stream>>>(w_out, wb2_sw, DD);
    mask_kernel<<<2, 256, 0, stream>>>(routes, maskg);

    gemm_mfma<1><<<dim3(THREE_D / 128, M_ROWS / 128), 256, 0, stream>>>(
        xb_sw, wb1_sw, b_qkv, nullptr, qbuf, k_ws, v_ws, THREE_D);

    blend_tr_kernel<<<256, 256, 0, stream>>>(k_ws, v_ws, K2g, Vtg);

    attn_kernel<<<256, 512, 0, stream>>>(qbuf, K2g, Vtg, maskg, attnsw);

    gemm_mfma<0><<<dim3(DD / 128, M_ROWS / 128), 256, 0, stream>>>(
        attnsw, wb2_sw, b_out, (float*)d_out, nullptr, nullptr, nullptr, DD);
}

// Round 6
// 163.388 us; speedup vs baseline: 3.2502x; 1.0521x over previous
//
#include <hip/hip_runtime.h>
#include <hip/hip_bf16.h>

#define BB 4
#define SS 512
#define DD 1024
#define HH 16
#define KR 64
#define HDIM 64
#define THREE_D 3072
#define M_ROWS 2048
#define SCALE_F 0.125f

typedef __attribute__((ext_vector_type(8))) short short8;
typedef __attribute__((ext_vector_type(4))) float floatx4;

union F8 { short8 s; unsigned int u[4]; unsigned short h[8]; };

__device__ inline float bfu(unsigned short h){ union{unsigned int u; float f;} c; c.u = ((unsigned int)h) << 16; return c.f; }
__device__ inline unsigned short f2bf(float f){
    union{float f; unsigned int u;} c; c.f = f;
    unsigned int u = c.u;
    return (unsigned short)((u + 0x7fffu + ((u >> 16) & 1u)) >> 16);   // RNE
}

#define GLOAD_LDS16(g, l)                                                     \
    __builtin_amdgcn_global_load_lds(                                         \
        (const __attribute__((address_space(1))) unsigned int*)(g),           \
        (__attribute__((address_space(3))) unsigned int*)(l), 16, 0, 0)

// ---------------------------------------------------------------------------
// cvt_A: x fp32 [2048][1024] -> bf16 swizzled chunks [mt][kt][c][r]
// ---------------------------------------------------------------------------
__global__ __launch_bounds__(256) void cvtA_kernel(const float* __restrict__ x,
                                                   unsigned short* __restrict__ out)
{
    int gid = blockIdx.x * 256 + threadIdx.x;
    int r  = gid & 127;
    int c  = (gid >> 7) & 3;
    int kt = (gid >> 9) & 31;
    int mt = gid >> 14;
    const float* src = x + ((size_t)(mt * 128 + r)) * 1024 + kt * 32 + c * 8;
    float4 a = *(const float4*)src;
    float4 b = *(const float4*)(src + 4);
    F8 o;
    o.h[0] = f2bf(a.x); o.h[1] = f2bf(a.y); o.h[2] = f2bf(a.z); o.h[3] = f2bf(a.w);
    o.h[4] = f2bf(b.x); o.h[5] = f2bf(b.y); o.h[6] = f2bf(b.z); o.h[7] = f2bf(b.w);
    *(uint4*)(out + (size_t)gid * 8) = *(uint4*)&o;
}

// ---------------------------------------------------------------------------
// cvt_B: W fp32 [1024][N] -> W^T bf16 swizzled chunks [nt][kt][c][r]
// ---------------------------------------------------------------------------
__global__ __launch_bounds__(256) void cvtB_kernel(const float* __restrict__ w,
                                                   unsigned short* __restrict__ out, int N)
{
    int gid = blockIdx.x * 256 + threadIdx.x;
    int r  = gid & 127;
    int c  = (gid >> 7) & 3;
    int kt = (gid >> 9) & 31;
    int nt = gid >> 14;
    int n = nt * 128 + r;
    int kbase = kt * 32 + c * 8;
    F8 o;
#pragma unroll
    for (int j = 0; j < 8; ++j)
        o.h[j] = f2bf(w[(size_t)(kbase + j) * N + n]);
    *(uint4*)(out + (size_t)gid * 8) = *(uint4*)&o;
}

// ---------------------------------------------------------------------------
// GEMM1 (QKV): 128x128 tile, BK=32, global_load_lds staging, LDS-assembled
// coalesced bf16 epilogue scattered into q/k/v [B,H,S,HD] bf16.
// ---------------------------------------------------------------------------
__global__ __launch_bounds__(256) void gemm_qkv(
    const unsigned short* __restrict__ Asw,
    const unsigned short* __restrict__ Bsw,
    const float* __restrict__ bias,
    unsigned short* __restrict__ qb, unsigned short* __restrict__ kb,
    unsigned short* __restrict__ vb)
{
    __shared__ __align__(16) unsigned short Sh[128 * 136];   // 34816 B
    unsigned short* Alds = Sh;
    unsigned short* Blds = Sh + 4096;

    const int tid  = threadIdx.x;
    const int lane = tid & 63;
    const int wid  = tid >> 6;
    const int l15  = lane & 15;
    const int quad = lane >> 4;
    const int wm   = (wid >> 1) * 64;
    const int wn   = (wid & 1) * 64;

    const unsigned short* Ak = Asw + (size_t)blockIdx.y * 131072;
    const unsigned short* Bk = Bsw + (size_t)blockIdx.x * 131072;

    floatx4 acc[4][4];
#pragma unroll
    for (int i = 0; i < 4; ++i)
#pragma unroll
        for (int j = 0; j < 4; ++j) acc[i][j] = (floatx4){0.f, 0.f, 0.f, 0.f};

    for (int kt = 0; kt < 32; ++kt) {
        const unsigned short* ga = Ak + kt * 4096 + wid * 1024 + lane * 8;
        const unsigned short* gb = Bk + kt * 4096 + wid * 1024 + lane * 8;
        GLOAD_LDS16(ga,       Alds + wid * 1024);
        GLOAD_LDS16(ga + 512, Alds + wid * 1024 + 512);
        GLOAD_LDS16(gb,       Blds + wid * 1024);
        GLOAD_LDS16(gb + 512, Blds + wid * 1024 + 512);
        __syncthreads();

        F8 af[4], bf[4];
#pragma unroll
        for (int mi = 0; mi < 4; ++mi)
            af[mi] = *(const F8*)(Alds + (size_t)(quad * 128 + wm + mi * 16 + l15) * 8);
#pragma unroll
        for (int ni = 0; ni < 4; ++ni)
            bf[ni] = *(const F8*)(Blds + (size_t)(quad * 128 + wn + ni * 16 + l15) * 8);
#pragma unroll
        for (int mi = 0; mi < 4; ++mi)
#pragma unroll
            for (int ni = 0; ni < 4; ++ni)
                acc[mi][ni] = __builtin_amdgcn_mfma_f32_16x16x32_bf16(
                    af[mi].s, bf[ni].s, acc[mi][ni], 0, 0, 0);
        __syncthreads();
    }

    const int m0 = blockIdx.y * 128;
    const int n0 = blockIdx.x * 128;

    // phase 1: acc -> bf16 tile in LDS (stride 136)
#pragma unroll
    for (int mi = 0; mi < 4; ++mi) {
#pragma unroll
        for (int ni = 0; ni < 4; ++ni) {
            int col = wn + ni * 16 + l15;
            float bv = bias[n0 + col];
#pragma unroll
            for (int r = 0; r < 4; ++r) {
                int row = wm + mi * 16 + quad * 4 + r;
                Sh[row * 136 + col] = f2bf(acc[mi][ni][r] + bv);
            }
        }
    }
    __syncthreads();

    // phase 2: coalesced 16B stores into q/k/v
    for (int i = tid; i < 2048; i += 256) {
        int rr = i >> 4, cc = i & 15;
        int grow = m0 + rr, gcol = n0 + cc * 8;
        int b = grow >> 9, s = grow & 511;
        int which = gcol >> 10, rem = gcol & 1023;
        int h = rem >> 6, hd = rem & 63;
        unsigned short* dst = (which == 0) ? qb : (which == 1) ? kb : vb;
        uint4 val = *(const uint4*)(Sh + rr * 136 + cc * 8);
        *(uint4*)(dst + (((size_t)(b * HH + h) * SS) + s) * HDIM + hd) = val;
    }
}

// ---------------------------------------------------------------------------
// GEMM2 (out proj): 64x128 tile -> 256 blocks (full CU coverage).
// 4 waves, each 64x32 (4m x 2n accs). fp32 output.
// ---------------------------------------------------------------------------
__global__ __launch_bounds__(256) void gemm_out(
    const unsigned short* __restrict__ Asw,   // [mt128][kt][c][r]
    const unsigned short* __restrict__ Bsw,
    const float* __restrict__ bias,
    float* __restrict__ Cout)
{
    __shared__ __align__(16) unsigned short Alds[2048];  // [c][r64]
    __shared__ __align__(16) unsigned short Blds[4096];

    const int tid  = threadIdx.x;
    const int lane = tid & 63;
    const int wid  = tid >> 6;
    const int l15  = lane & 15;
    const int quad = lane >> 4;
    const int mt64 = blockIdx.y;              // 0..31
    const int mt   = mt64 >> 1;
    const int rh   = (mt64 & 1) * 64;
    const int nt   = blockIdx.x;              // 0..7
    const int wn   = wid * 32;

    floatx4 acc[4][2];
#pragma unroll
    for (int i = 0; i < 4; ++i)
#pragma unroll
        for (int j = 0; j < 2; ++j) acc[i][j] = (floatx4){0.f, 0.f, 0.f, 0.f};

    for (int kt = 0; kt < 32; ++kt) {
        const unsigned short* ga = Asw + ((size_t)(mt * 32 + kt) * 4 + wid) * 1024 + (rh + lane) * 8;
        const unsigned short* gb = Bsw + (size_t)(nt * 32 + kt) * 4096 + wid * 1024 + lane * 8;
        GLOAD_LDS16(ga,       Alds + (wid * 64 + lane) * 8);
        GLOAD_LDS16(gb,       Blds + wid * 1024 + lane * 8);
        GLOAD_LDS16(gb + 512, Blds + wid * 1024 + 512 + lane * 8);
        __syncthreads();

        F8 af[4], bf[2];
#pragma unroll
        for (int mi = 0; mi < 4; ++mi)
            af[mi] = *(const F8*)(Alds + (size_t)(quad * 64 + mi * 16 + l15) * 8);
#pragma unroll
        for (int ni = 0; ni < 2; ++ni)
            bf[ni] = *(const F8*)(Blds + (size_t)(quad * 128 + wn + ni * 16 + l15) * 8);
#pragma unroll
        for (int mi = 0; mi < 4; ++mi)
#pragma unroll
            for (int ni = 0; ni < 2; ++ni)
                acc[mi][ni] = __builtin_amdgcn_mfma_f32_16x16x32_bf16(
                    af[mi].s, bf[ni].s, acc[mi][ni], 0, 0, 0);
        __syncthreads();
    }

    const int m0 = mt64 * 64;
    const int n0 = nt * 128;
#pragma unroll
    for (int mi = 0; mi < 4; ++mi) {
#pragma unroll
        for (int ni = 0; ni < 2; ++ni) {
            int col = n0 + wn + ni * 16 + l15;
            float bv = bias[col];
#pragma unroll
            for (int r = 0; r < 4; ++r) {
                int row = m0 + mi * 16 + quad * 4 + r;
                Cout[(size_t)row * DD + col] = acc[mi][ni][r] + bv;
            }
        }
    }
}

// ---------------------------------------------------------------------------
// blend + transpose (bf16 in): K'[s][d] bf16, V't[d][s] bf16 (per bh)
// ---------------------------------------------------------------------------
__global__ __launch_bounds__(256) void blend_tr_kernel(
    const unsigned short* __restrict__ kb, const unsigned short* __restrict__ vb,
    unsigned short* __restrict__ K2g, unsigned short* __restrict__ Vtg)
{
    __shared__ float kt[130][65];
    __shared__ float vt[130][65];
    const int bh = blockIdx.x >> 2;
    const int sb = (blockIdx.x & 3) * 128;
    const int tid = threadIdx.x;
    const unsigned short* kbase = kb + (size_t)bh * SS * HDIM;
    const unsigned short* vbase = vb + (size_t)bh * SS * HDIM;

    for (int i = tid; i < 130 * 8; i += 256) {
        int row = i >> 3, c8 = (i & 7) << 3;
        int s = sb + row - 1; s = s < 0 ? 0 : (s > SS - 1 ? SS - 1 : s);
        F8 kk = *(const F8*)(kbase + (size_t)s * 64 + c8);
        F8 vv = *(const F8*)(vbase + (size_t)s * 64 + c8);
#pragma unroll
        for (int j = 0; j < 8; ++j) {
            kt[row][c8 + j] = bfu(kk.h[j]);
            vt[row][c8 + j] = bfu(vv.h[j]);
        }
    }
    __syncthreads();

    for (int i = tid; i < 128 * 16; i += 256) {
        int sl = i >> 4, c4 = (i & 15) << 2;
        ushort4 o;
        o.x = f2bf(0.75f * kt[sl+1][c4+0] + 0.125f * (kt[sl][c4+0] + kt[sl+2][c4+0]));
        o.y = f2bf(0.75f * kt[sl+1][c4+1] + 0.125f * (kt[sl][c4+1] + kt[sl+2][c4+1]));
        o.z = f2bf(0.75f * kt[sl+1][c4+2] + 0.125f * (kt[sl][c4+2] + kt[sl+2][c4+2]));
        o.w = f2bf(0.75f * kt[sl+1][c4+3] + 0.125f * (kt[sl][c4+3] + kt[sl+2][c4+3]));
        *(ushort4*)(K2g + ((size_t)bh * SS + sb + sl) * 64 + c4) = o;
    }
    for (int i = tid; i < 64 * 32; i += 256) {
        int d = i >> 5, s4 = (i & 31) << 2;
        ushort4 o;
        o.x = f2bf(0.75f * vt[s4+1][d] + 0.125f * (vt[s4+0][d] + vt[s4+2][d]));
        o.y = f2bf(0.75f * vt[s4+2][d] + 0.125f * (vt[s4+1][d] + vt[s4+3][d]));
        o.z = f2bf(0.75f * vt[s4+3][d] + 0.125f * (vt[s4+2][d] + vt[s4+4][d]));
        o.w = f2bf(0.75f * vt[s4+4][d] + 0.125f * (vt[s4+3][d] + vt[s4+5][d]));
        *(ushort4*)(Vtg + ((size_t)bh * 64 + d) * SS + sb + s4) = o;
    }
}

// ---------------------------------------------------------------------------
__global__ __launch_bounds__(256) void mask_kernel(const int* __restrict__ routes,
                                                   unsigned int* __restrict__ maskg)
{
    int q = blockIdx.x * 256 + threadIdx.x;
    unsigned int w[16];
#pragma unroll
    for (int i = 0; i < 16; ++i) w[i] = 0u;
    for (int j = 0; j < KR; ++j) {
        int r = routes[q * KR + j];
        if (r <= q) w[r >> 5] |= 1u << (r & 31);
    }
#pragma unroll
    for (int sw = 0; sw < 16; ++sw) maskg[sw * SS + q] = w[sw];
}

// ---------------------------------------------------------------------------
// Dense masked flash attention via MFMA; swizzled-chunk output for gemm2.
// ---------------------------------------------------------------------------
__global__ __launch_bounds__(512, 2) void attn_kernel(
    const unsigned short* __restrict__ qb,
    const unsigned short* __restrict__ K2g,
    const unsigned short* __restrict__ Vtg,
    const unsigned int* __restrict__ maskg,
    unsigned short* __restrict__ attn_sw)
{
    __shared__ __align__(16) unsigned short Ks[512 * 64];
    __shared__ __align__(16) unsigned short Vs[64 * 512];
    __shared__ __align__(16) unsigned short Ps[8 * 16 * 64];

    const int bh = blockIdx.x >> 2;
    const int qt = blockIdx.x & 3;
    const int b = bh >> 4, h = bh & 15;
    const int tid  = threadIdx.x;
    const int lane = tid & 63;
    const int wid  = tid >> 6;
    const int l15  = lane & 15;
    const int quad = lane >> 4;

    {
        const uint4* src = (const uint4*)(K2g + (size_t)bh * (SS * 64));
        uint4* dst = (uint4*)Ks;
        for (int c = tid; c < 4096; c += 512) {
            int s = c >> 3, cc = c & 7;
            dst[(s << 3) | (cc ^ (s & 7))] = src[c];
        }
        const uint4* srcv = (const uint4*)(Vtg + (size_t)bh * (64 * SS));
        uint4* dstv = (uint4*)Vs;
        for (int c = tid; c < 4096; c += 512) {
            int d = c >> 6, sc = c & 63;
            dstv[(d << 6) | (sc & 56) | ((sc ^ d) & 7)] = srcv[c];
        }
    }
    __syncthreads();

    const int qbase = qt * 128 + wid * 16;
    const int q = qbase + l15;

    F8 qf[2];
    {
        const unsigned short* qrow = qb + ((size_t)bh * SS + q) * 64;
        qf[0] = *(const F8*)(qrow + quad * 8);
        qf[1] = *(const F8*)(qrow + 32 + quad * 8);
    }

    floatx4 accS[32];
#pragma unroll
    for (int st = 0; st < 32; ++st) {
        int srow = st * 16 + l15;
        const F8 k0 = *(const F8*)(Ks + (((srow << 3) | ( quad      ^ (srow & 7))) << 3));
        const F8 k1 = *(const F8*)(Ks + (((srow << 3) | ((4 + quad) ^ (srow & 7))) << 3));
        floatx4 a = (floatx4){0.f, 0.f, 0.f, 0.f};
        a = __builtin_amdgcn_mfma_f32_16x16x32_bf16(k0.s, qf[0].s, a, 0, 0, 0);
        a = __builtin_amdgcn_mfma_f32_16x16x32_bf16(k1.s, qf[1].s, a, 0, 0, 0);
        accS[st] = a;
    }

    float m = -1e30f;
    unsigned int mw = 0;
#pragma unroll
    for (int st = 0; st < 32; ++st) {
        if ((st & 1) == 0) mw = maskg[(st >> 1) * SS + q];
        int sbase = (st & 1) * 16 + quad * 4;
        floatx4 a = accS[st];
#pragma unroll
        for (int r = 0; r < 4; ++r) {
            float v = ((mw >> (sbase + r)) & 1u) ? a[r] * SCALE_F : -1e30f;
            a[r] = v;
            m = fmaxf(m, v);
        }
        accS[st] = a;
    }
    m = fmaxf(m, __shfl_xor(m, 16));
    m = fmaxf(m, __shfl_xor(m, 32));

    floatx4 accO[4];
#pragma unroll
    for (int dt = 0; dt < 4; ++dt) accO[dt] = (floatx4){0.f, 0.f, 0.f, 0.f};
    float lsum = 0.f;
    unsigned int* Pw = (unsigned int*)Ps + wid * 512;

#pragma unroll
    for (int ch = 0; ch < 8; ++ch) {
#pragma unroll
        for (int t = 0; t < 4; ++t) {
            floatx4 a = accS[ch * 4 + t];
            float e0 = __expf(a[0] - m), e1 = __expf(a[1] - m);
            float e2 = __expf(a[2] - m), e3 = __expf(a[3] - m);
            lsum += (e0 + e1) + (e2 + e3);
            unsigned int w0 = (unsigned int)f2bf(e0) | ((unsigned int)f2bf(e1) << 16);
            unsigned int w1 = (unsigned int)f2bf(e2) | ((unsigned int)f2bf(e3) << 16);
            int off0 = t * 8 + quad * 2;
            int off1 = off0 + 1;
            Pw[l15 * 32 + ((((off0 >> 2) ^ (l15 & 7)) << 2) | (off0 & 3))] = w0;
            Pw[l15 * 32 + ((((off1 >> 2) ^ (l15 & 7)) << 2) | (off1 & 3))] = w1;
        }
        F8 pa[2];
#pragma unroll
        for (int ks = 0; ks < 2; ++ks) {
            int ci = ks * 4 + quad;
            pa[ks] = *(const F8*)((const unsigned short*)(Pw + l15 * 32) +
                                  ((ci ^ (l15 & 7)) << 3));
        }
#pragma unroll
        for (int dt = 0; dt < 4; ++dt) {
            int d = dt * 16 + l15;
#pragma unroll
            for (int ks = 0; ks < 2; ++ks) {
                int sc = ch * 8 + ks * 4 + quad;
                const F8 bv = *(const F8*)(Vs + (((d << 6) | (sc & 56) | ((sc ^ d) & 7)) << 3));
                accO[dt] = __builtin_amdgcn_mfma_f32_16x16x32_bf16(pa[ks].s, bv.s, accO[dt], 0, 0, 0);
            }
        }
    }

    lsum += __shfl_xor(lsum, 16);
    lsum += __shfl_xor(lsum, 32);
    float inv = 1.0f / lsum;

    unsigned short* Ow = Ps + wid * 1024;
#pragma unroll
    for (int r = 0; r < 4; ++r) {
        float invr = __shfl(inv, quad * 4 + r);
#pragma unroll
        for (int dt = 0; dt < 4; ++dt)
            Ow[(quad * 4 + r) * 64 + dt * 16 + l15] = f2bf(accO[dt][r] * invr);
    }
#pragma unroll
    for (int i = 0; i < 2; ++i) {
        int ch = i * 64 + lane;
        int qlocal = ch >> 3, j = ch & 7;
        int qq = qt * 128 + wid * 16 + qlocal;
        int mrow = b * SS + qq;
        int mt = mrow >> 7, rr = mrow & 127;
        int kt2 = h * 2 + (j >> 2), c = j & 3;
        size_t gid = (((size_t)(mt * 32 + kt2) * 4 + c) * 128 + rr);
        *(uint4*)(attn_sw + gid * 8) = *(const uint4*)(Ow + qlocal * 64 + j * 8);
    }
}

// ---------------------------------------------------------------------------
extern "C" void kernel_launch(void* const* d_in, const int* in_sizes, int n_in,
                              void* d_out, int out_size, void* d_ws, size_t ws_size,
                              hipStream_t stream)
{
    const float* x     = (const float*)d_in[0];
    const float* w_qkv = (const float*)d_in[1];
    const float* b_qkv = (const float*)d_in[2];
    const float* w_out = (const float*)d_in[3];
    const float* b_out = (const float*)d_in[4];
    const int* routes  = (const int*)d_in[5];

    char* w = (char*)d_ws;
    unsigned short* xb_sw  = (unsigned short*)(w);                 // 4 MB
    unsigned short* wb1_sw = (unsigned short*)(w + (4u  << 20));   // 6 MB
    unsigned short* wb2_sw = (unsigned short*)(w + (10u << 20));   // 2 MB
    unsigned short* qbuf   = (unsigned short*)(w + (12u << 20));   // 4 MB bf16
    unsigned short* kbuf   = (unsigned short*)(w + (16u << 20));   // 4 MB bf16
    unsigned short* vbuf   = (unsigned short*)(w + (20u << 20));   // 4 MB bf16
    unsigned short* K2g    = (unsigned short*)(w + (24u << 20));   // 4 MB
    unsigned short* Vtg    = (unsigned short*)(w + (28u << 20));   // 4 MB
    unsigned short* attnsw = (unsigned short*)(w + (32u << 20));   // 4 MB
    unsigned int*   maskg  = (unsigned int*)(w + (36u << 20));     // 32 KB

    cvtA_kernel<<<1024, 256, 0, stream>>>(x, xb_sw);
    cvtB_kernel<<<1536, 256, 0, stream>>>(w_qkv, wb1_sw, THREE_D);
    cvtB_kernel<<<512, 256, 0, stream>>>(w_out, wb2_sw, DD);
    mask_kernel<<<2, 256, 0, stream>>>(routes, maskg);

    gemm_qkv<<<dim3(THREE_D / 128, M_ROWS / 128), 256, 0, stream>>>(
        xb_sw, wb1_sw, b_qkv, qbuf, kbuf, vbuf);

    blend_tr_kernel<<<256, 256, 0, stream>>>(kbuf, vbuf, K2g, Vtg);

    attn_kernel<<<256, 512, 0, stream>>>(qbuf, K2g, Vtg, maskg, attnsw);

    gemm_out<<<dim3(DD / 128, M_ROWS / 64), 256, 0, stream>>>(
        attnsw, wb2_sw, b_out, (float*)d_out);
}

// Round 7
// 151.363 us; speedup vs baseline: 3.5084x; 1.0794x over previous
//
#include <hip/hip_runtime.h>
#include <hip/hip_bf16.h>

#define BB 4
#define SS 512
#define DD 1024
#define HH 16
#define KR 64
#define HDIM 64
#define THREE_D 3072
#define M_ROWS 2048
#define SCALE_F 0.125f

typedef __attribute__((ext_vector_type(8))) short short8;
typedef __attribute__((ext_vector_type(4))) float floatx4;

union F8 { short8 s; unsigned int u[4]; unsigned short h[8]; };

__device__ inline float bfu(unsigned short h){ union{unsigned int u; float f;} c; c.u = ((unsigned int)h) << 16; return c.f; }
__device__ inline unsigned short f2bf(float f){
    union{float f; unsigned int u;} c; c.f = f;
    unsigned int u = c.u;
    return (unsigned short)((u + 0x7fffu + ((u >> 16) & 1u)) >> 16);   // RNE
}

#define GLOAD_LDS16(g, l)                                                     \
    __builtin_amdgcn_global_load_lds(                                         \
        (const __attribute__((address_space(1))) unsigned int*)(g),           \
        (__attribute__((address_space(3))) unsigned int*)(l), 16, 0, 0)

// ---------------------------------------------------------------------------
// prep: fused cvtA (x->swizzled bf16) + cvtB(w_qkv) + cvtB(w_out) + mask
// blocks [0,1024) = A, [1024,2560) = w_qkv, [2560,3072) = w_out, [3072,3074) = mask
// ---------------------------------------------------------------------------
__global__ __launch_bounds__(256) void prep_kernel(
    const float* __restrict__ x, const float* __restrict__ w_qkv,
    const float* __restrict__ w_out, const int* __restrict__ routes,
    unsigned short* __restrict__ xb_sw, unsigned short* __restrict__ wb1_sw,
    unsigned short* __restrict__ wb2_sw, unsigned int* __restrict__ maskg)
{
    const int bx = blockIdx.x;
    const int tid = threadIdx.x;
    if (bx < 1024) {
        int gid = bx * 256 + tid;
        int r  = gid & 127;
        int c  = (gid >> 7) & 3;
        int kt = (gid >> 9) & 31;
        int mt = gid >> 14;
        const float* src = x + ((size_t)(mt * 128 + r)) * 1024 + kt * 32 + c * 8;
        float4 a = *(const float4*)src;
        float4 b = *(const float4*)(src + 4);
        F8 o;
        o.h[0] = f2bf(a.x); o.h[1] = f2bf(a.y); o.h[2] = f2bf(a.z); o.h[3] = f2bf(a.w);
        o.h[4] = f2bf(b.x); o.h[5] = f2bf(b.y); o.h[6] = f2bf(b.z); o.h[7] = f2bf(b.w);
        *(uint4*)(xb_sw + (size_t)gid * 8) = *(uint4*)&o;
    } else if (bx < 3072) {
        const float* w;
        unsigned short* out;
        int gid, N;
        if (bx < 2560) { w = w_qkv; out = wb1_sw; N = THREE_D; gid = (bx - 1024) * 256 + tid; }
        else           { w = w_out; out = wb2_sw; N = DD;      gid = (bx - 2560) * 256 + tid; }
        int r  = gid & 127;
        int c  = (gid >> 7) & 3;
        int kt = (gid >> 9) & 31;
        int nt = gid >> 14;
        int n = nt * 128 + r;
        int kbase = kt * 32 + c * 8;
        F8 o;
#pragma unroll
        for (int j = 0; j < 8; ++j)
            o.h[j] = f2bf(w[(size_t)(kbase + j) * N + n]);
        *(uint4*)(out + (size_t)gid * 8) = *(uint4*)&o;
    } else {
        int q = (bx - 3072) * 256 + tid;
        unsigned int w[16];
#pragma unroll
        for (int i = 0; i < 16; ++i) w[i] = 0u;
        for (int j = 0; j < KR; ++j) {
            int r = routes[q * KR + j];
            if (r <= q) w[r >> 5] |= 1u << (r & 31);
        }
#pragma unroll
        for (int sw = 0; sw < 16; ++sw) maskg[sw * SS + q] = w[sw];
    }
}

// ---------------------------------------------------------------------------
// GEMM1 (QKV): 128x128 tile, BK=64 (16 barriers), global_load_lds staging,
// LDS-assembled coalesced bf16 epilogue into q/k/v [B,H,S,HD] bf16.
// ---------------------------------------------------------------------------
__global__ __launch_bounds__(256) void gemm_qkv(
    const unsigned short* __restrict__ Asw,
    const unsigned short* __restrict__ Bsw,
    const float* __restrict__ bias,
    unsigned short* __restrict__ qb, unsigned short* __restrict__ kb,
    unsigned short* __restrict__ vb)
{
    __shared__ __align__(16) unsigned short Sh[17408];   // 34816 B (union)
    unsigned short* Alds = Sh;           // 8192 shorts (128x64)
    unsigned short* Blds = Sh + 8192;    // 8192 shorts

    const int tid  = threadIdx.x;
    const int lane = tid & 63;
    const int wid  = tid >> 6;
    const int l15  = lane & 15;
    const int quad = lane >> 4;
    const int wm   = (wid >> 1) * 64;
    const int wn   = (wid & 1) * 64;

    const unsigned short* Ak = Asw + (size_t)blockIdx.y * 131072;
    const unsigned short* Bk = Bsw + (size_t)blockIdx.x * 131072;

    floatx4 acc[4][4];
#pragma unroll
    for (int i = 0; i < 4; ++i)
#pragma unroll
        for (int j = 0; j < 4; ++j) acc[i][j] = (floatx4){0.f, 0.f, 0.f, 0.f};

    for (int kt2 = 0; kt2 < 16; ++kt2) {
#pragma unroll
        for (int kh = 0; kh < 2; ++kh) {
            const unsigned short* ga = Ak + (kt2 * 2 + kh) * 4096 + wid * 1024 + lane * 8;
            const unsigned short* gb = Bk + (kt2 * 2 + kh) * 4096 + wid * 1024 + lane * 8;
            GLOAD_LDS16(ga,       Alds + kh * 4096 + wid * 1024 + lane * 8);
            GLOAD_LDS16(ga + 512, Alds + kh * 4096 + wid * 1024 + 512 + lane * 8);
            GLOAD_LDS16(gb,       Blds + kh * 4096 + wid * 1024 + lane * 8);
            GLOAD_LDS16(gb + 512, Blds + kh * 4096 + wid * 1024 + 512 + lane * 8);
        }
        __syncthreads();

#pragma unroll
        for (int kh = 0; kh < 2; ++kh) {
            F8 af[4], bf[4];
#pragma unroll
            for (int mi = 0; mi < 4; ++mi)
                af[mi] = *(const F8*)(Alds + kh * 4096 + (size_t)(quad * 128 + wm + mi * 16 + l15) * 8);
#pragma unroll
            for (int ni = 0; ni < 4; ++ni)
                bf[ni] = *(const F8*)(Blds + kh * 4096 + (size_t)(quad * 128 + wn + ni * 16 + l15) * 8);
#pragma unroll
            for (int mi = 0; mi < 4; ++mi)
#pragma unroll
                for (int ni = 0; ni < 4; ++ni)
                    acc[mi][ni] = __builtin_amdgcn_mfma_f32_16x16x32_bf16(
                        af[mi].s, bf[ni].s, acc[mi][ni], 0, 0, 0);
        }
        __syncthreads();
    }

    const int m0 = blockIdx.y * 128;
    const int n0 = blockIdx.x * 128;

    // phase 1: acc -> bf16 tile in LDS (stride 136)
#pragma unroll
    for (int mi = 0; mi < 4; ++mi) {
#pragma unroll
        for (int ni = 0; ni < 4; ++ni) {
            int col = wn + ni * 16 + l15;
            float bv = bias[n0 + col];
#pragma unroll
            for (int r = 0; r < 4; ++r) {
                int row = wm + mi * 16 + quad * 4 + r;
                Sh[row * 136 + col] = f2bf(acc[mi][ni][r] + bv);
            }
        }
    }
    __syncthreads();

    // phase 2: coalesced 16B stores into q/k/v
    for (int i = tid; i < 2048; i += 256) {
        int rr = i >> 4, cc = i & 15;
        int grow = m0 + rr, gcol = n0 + cc * 8;
        int b = grow >> 9, s = grow & 511;
        int which = gcol >> 10, rem = gcol & 1023;
        int h = rem >> 6, hd = rem & 63;
        unsigned short* dst = (which == 0) ? qb : (which == 1) ? kb : vb;
        uint4 val = *(const uint4*)(Sh + rr * 136 + cc * 8);
        *(uint4*)(dst + (((size_t)(b * HH + h) * SS) + s) * HDIM + hd) = val;
    }
}

// ---------------------------------------------------------------------------
// GEMM2 (out proj): 64x128 tile, BK=64 -> 256 blocks, fp32 output.
// ---------------------------------------------------------------------------
__global__ __launch_bounds__(256) void gemm_out(
    const unsigned short* __restrict__ Asw,
    const unsigned short* __restrict__ Bsw,
    const float* __restrict__ bias,
    float* __restrict__ Cout)
{
    __shared__ __align__(16) unsigned short Alds[4096];  // 2 kh x (64x32)
    __shared__ __align__(16) unsigned short Blds[8192];  // 2 kh x (128x32)

    const int tid  = threadIdx.x;
    const int lane = tid & 63;
    const int wid  = tid >> 6;
    const int l15  = lane & 15;
    const int quad = lane >> 4;
    const int mt64 = blockIdx.y;
    const int mt   = mt64 >> 1;
    const int rh   = (mt64 & 1) * 64;
    const int nt   = blockIdx.x;
    const int wn   = wid * 32;

    floatx4 acc[4][2];
#pragma unroll
    for (int i = 0; i < 4; ++i)
#pragma unroll
        for (int j = 0; j < 2; ++j) acc[i][j] = (floatx4){0.f, 0.f, 0.f, 0.f};

    for (int kt2 = 0; kt2 < 16; ++kt2) {
#pragma unroll
        for (int kh = 0; kh < 2; ++kh) {
            int kt = kt2 * 2 + kh;
            const unsigned short* ga = Asw + ((size_t)(mt * 32 + kt) * 4 + wid) * 1024 + (rh + lane) * 8;
            const unsigned short* gb = Bsw + (size_t)(nt * 32 + kt) * 4096 + wid * 1024 + lane * 8;
            GLOAD_LDS16(ga,       Alds + kh * 2048 + wid * 512 + lane * 8);
            GLOAD_LDS16(gb,       Blds + kh * 4096 + wid * 1024 + lane * 8);
            GLOAD_LDS16(gb + 512, Blds + kh * 4096 + wid * 1024 + 512 + lane * 8);
        }
        __syncthreads();

#pragma unroll
        for (int kh = 0; kh < 2; ++kh) {
            F8 af[4], bf[2];
#pragma unroll
            for (int mi = 0; mi < 4; ++mi)
                af[mi] = *(const F8*)(Alds + kh * 2048 + (size_t)(quad * 64 + mi * 16 + l15) * 8);
#pragma unroll
            for (int ni = 0; ni < 2; ++ni)
                bf[ni] = *(const F8*)(Blds + kh * 4096 + (size_t)(quad * 128 + wn + ni * 16 + l15) * 8);
#pragma unroll
            for (int mi = 0; mi < 4; ++mi)
#pragma unroll
                for (int ni = 0; ni < 2; ++ni)
                    acc[mi][ni] = __builtin_amdgcn_mfma_f32_16x16x32_bf16(
                        af[mi].s, bf[ni].s, acc[mi][ni], 0, 0, 0);
        }
        __syncthreads();
    }

    const int m0 = mt64 * 64;
    const int n0 = nt * 128;
#pragma unroll
    for (int mi = 0; mi < 4; ++mi) {
#pragma unroll
        for (int ni = 0; ni < 2; ++ni) {
            int col = n0 + wn + ni * 16 + l15;
            float bv = bias[col];
#pragma unroll
            for (int r = 0; r < 4; ++r) {
                int row = m0 + mi * 16 + quad * 4 + r;
                Cout[(size_t)row * DD + col] = acc[mi][ni][r] + bv;
            }
        }
    }
}

// ---------------------------------------------------------------------------
// blend V only: V't[d][s] bf16 (per bh); K' is blended inline in attn.
// ---------------------------------------------------------------------------
__global__ __launch_bounds__(256) void blend_v_kernel(
    const unsigned short* __restrict__ vb, unsigned short* __restrict__ Vtg)
{
    __shared__ float vt[130][65];
    const int bh = blockIdx.x >> 2;
    const int sb = (blockIdx.x & 3) * 128;
    const int tid = threadIdx.x;
    const unsigned short* vbase = vb + (size_t)bh * SS * HDIM;

    for (int i = tid; i < 130 * 8; i += 256) {
        int row = i >> 3, c8 = (i & 7) << 3;
        int s = sb + row - 1; s = s < 0 ? 0 : (s > SS - 1 ? SS - 1 : s);
        F8 vv = *(const F8*)(vbase + (size_t)s * 64 + c8);
#pragma unroll
        for (int j = 0; j < 8; ++j) vt[row][c8 + j] = bfu(vv.h[j]);
    }
    __syncthreads();

    for (int i = tid; i < 64 * 32; i += 256) {
        int d = i >> 5, s4 = (i & 31) << 2;
        ushort4 o;
        o.x = f2bf(0.75f * vt[s4+1][d] + 0.125f * (vt[s4+0][d] + vt[s4+2][d]));
        o.y = f2bf(0.75f * vt[s4+2][d] + 0.125f * (vt[s4+1][d] + vt[s4+3][d]));
        o.z = f2bf(0.75f * vt[s4+3][d] + 0.125f * (vt[s4+2][d] + vt[s4+4][d]));
        o.w = f2bf(0.75f * vt[s4+4][d] + 0.125f * (vt[s4+3][d] + vt[s4+5][d]));
        *(ushort4*)(Vtg + ((size_t)bh * 64 + d) * SS + sb + s4) = o;
    }
}

// ---------------------------------------------------------------------------
// Dense masked flash attention via MFMA; K' blended inline during staging;
// swizzled-chunk output for gemm2.
// ---------------------------------------------------------------------------
__global__ __launch_bounds__(512, 2) void attn_kernel(
    const unsigned short* __restrict__ qb,
    const unsigned short* __restrict__ kbuf,  // raw K bf16 [B,H,S,HD]
    const unsigned short* __restrict__ Vtg,
    const unsigned int* __restrict__ maskg,
    unsigned short* __restrict__ attn_sw)
{
    __shared__ __align__(16) unsigned short Ks[512 * 64];
    __shared__ __align__(16) unsigned short Vs[64 * 512];
    __shared__ __align__(16) unsigned short Ps[8 * 16 * 64];

    const int bh = blockIdx.x >> 2;
    const int qt = blockIdx.x & 3;
    const int b = bh >> 4, h = bh & 15;
    const int tid  = threadIdx.x;
    const int lane = tid & 63;
    const int wid  = tid >> 6;
    const int l15  = lane & 15;
    const int quad = lane >> 4;

    {
        // K' = blend(K) computed inline (kbuf is L2-hot, 64 KB per bh)
        const unsigned short* kbh = kbuf + (size_t)bh * (SS * 64);
        uint4* dst = (uint4*)Ks;
        for (int c = tid; c < 4096; c += 512) {
            int s = c >> 3, cc = c & 7;
            int sm = s ? s - 1 : 0;
            int sp = (s < SS - 1) ? s + 1 : SS - 1;
            F8 k0 = *(const F8*)(kbh + (size_t)s  * 64 + cc * 8);
            F8 km = *(const F8*)(kbh + (size_t)sm * 64 + cc * 8);
            F8 kp = *(const F8*)(kbh + (size_t)sp * 64 + cc * 8);
            F8 o;
#pragma unroll
            for (int j = 0; j < 8; ++j)
                o.h[j] = f2bf(0.75f * bfu(k0.h[j]) + 0.125f * (bfu(km.h[j]) + bfu(kp.h[j])));
            dst[(s << 3) | (cc ^ (s & 7))] = *(uint4*)&o;
        }
        const uint4* srcv = (const uint4*)(Vtg + (size_t)bh * (64 * SS));
        uint4* dstv = (uint4*)Vs;
        for (int c = tid; c < 4096; c += 512) {
            int d = c >> 6, sc = c & 63;
            dstv[(d << 6) | (sc & 56) | ((sc ^ d) & 7)] = srcv[c];
        }
    }
    __syncthreads();

    const int qbase = qt * 128 + wid * 16;
    const int q = qbase + l15;

    F8 qf[2];
    {
        const unsigned short* qrow = qb + ((size_t)bh * SS + q) * 64;
        qf[0] = *(const F8*)(qrow + quad * 8);
        qf[1] = *(const F8*)(qrow + 32 + quad * 8);
    }

    floatx4 accS[32];
#pragma unroll
    for (int st = 0; st < 32; ++st) {
        int srow = st * 16 + l15;
        const F8 k0 = *(const F8*)(Ks + (((srow << 3) | ( quad      ^ (srow & 7))) << 3));
        const F8 k1 = *(const F8*)(Ks + (((srow << 3) | ((4 + quad) ^ (srow & 7))) << 3));
        floatx4 a = (floatx4){0.f, 0.f, 0.f, 0.f};
        a = __builtin_amdgcn_mfma_f32_16x16x32_bf16(k0.s, qf[0].s, a, 0, 0, 0);
        a = __builtin_amdgcn_mfma_f32_16x16x32_bf16(k1.s, qf[1].s, a, 0, 0, 0);
        accS[st] = a;
    }

    float m = -1e30f;
    unsigned int mw = 0;
#pragma unroll
    for (int st = 0; st < 32; ++st) {
        if ((st & 1) == 0) mw = maskg[(st >> 1) * SS + q];
        int sbase = (st & 1) * 16 + quad * 4;
        floatx4 a = accS[st];
#pragma unroll
        for (int r = 0; r < 4; ++r) {
            float v = ((mw >> (sbase + r)) & 1u) ? a[r] * SCALE_F : -1e30f;
            a[r] = v;
            m = fmaxf(m, v);
        }
        accS[st] = a;
    }
    m = fmaxf(m, __shfl_xor(m, 16));
    m = fmaxf(m, __shfl_xor(m, 32));

    floatx4 accO[4];
#pragma unroll
    for (int dt = 0; dt < 4; ++dt) accO[dt] = (floatx4){0.f, 0.f, 0.f, 0.f};
    float lsum = 0.f;
    unsigned int* Pw = (unsigned int*)Ps + wid * 512;

#pragma unroll
    for (int ch = 0; ch < 8; ++ch) {
#pragma unroll
        for (int t = 0; t < 4; ++t) {
            floatx4 a = accS[ch * 4 + t];
            float e0 = __expf(a[0] - m), e1 = __expf(a[1] - m);
            float e2 = __expf(a[2] - m), e3 = __expf(a[3] - m);
            lsum += (e0 + e1) + (e2 + e3);
            unsigned int w0 = (unsigned int)f2bf(e0) | ((unsigned int)f2bf(e1) << 16);
            unsigned int w1 = (unsigned int)f2bf(e2) | ((unsigned int)f2bf(e3) << 16);
            int off0 = t * 8 + quad * 2;
            int off1 = off0 + 1;
            Pw[l15 * 32 + ((((off0 >> 2) ^ (l15 & 7)) << 2) | (off0 & 3))] = w0;
            Pw[l15 * 32 + ((((off1 >> 2) ^ (l15 & 7)) << 2) | (off1 & 3))] = w1;
        }
        F8 pa[2];
#pragma unroll
        for (int ks = 0; ks < 2; ++ks) {
            int ci = ks * 4 + quad;
            pa[ks] = *(const F8*)((const unsigned short*)(Pw + l15 * 32) +
                                  ((ci ^ (l15 & 7)) << 3));
        }
#pragma unroll
        for (int dt = 0; dt < 4; ++dt) {
            int d = dt * 16 + l15;
#pragma unroll
            for (int ks = 0; ks < 2; ++ks) {
                int sc = ch * 8 + ks * 4 + quad;
                const F8 bv = *(const F8*)(Vs + (((d << 6) | (sc & 56) | ((sc ^ d) & 7)) << 3));
                accO[dt] = __builtin_amdgcn_mfma_f32_16x16x32_bf16(pa[ks].s, bv.s, accO[dt], 0, 0, 0);
            }
        }
    }

    lsum += __shfl_xor(lsum, 16);
    lsum += __shfl_xor(lsum, 32);
    float inv = 1.0f / lsum;

    unsigned short* Ow = Ps + wid * 1024;
#pragma unroll
    for (int r = 0; r < 4; ++r) {
        float invr = __shfl(inv, quad * 4 + r);
#pragma unroll
        for (int dt = 0; dt < 4; ++dt)
            Ow[(quad * 4 + r) * 64 + dt * 16 + l15] = f2bf(accO[dt][r] * invr);
    }
#pragma unroll
    for (int i = 0; i < 2; ++i) {
        int ch = i * 64 + lane;
        int qlocal = ch >> 3, j = ch & 7;
        int qq = qt * 128 + wid * 16 + qlocal;
        int mrow = b * SS + qq;
        int mt = mrow >> 7, rr = mrow & 127;
        int kt2 = h * 2 + (j >> 2), c = j & 3;
        size_t gid = (((size_t)(mt * 32 + kt2) * 4 + c) * 128 + rr);
        *(uint4*)(attn_sw + gid * 8) = *(const uint4*)(Ow + qlocal * 64 + j * 8);
    }
}

// ---------------------------------------------------------------------------
extern "C" void kernel_launch(void* const* d_in, const int* in_sizes, int n_in,
                              void* d_out, int out_size, void* d_ws, size_t ws_size,
                              hipStream_t stream)
{
    const float* x     = (const float*)d_in[0];
    const float* w_qkv = (const float*)d_in[1];
    const float* b_qkv = (const float*)d_in[2];
    const float* w_out = (const float*)d_in[3];
    const float* b_out = (const float*)d_in[4];
    const int* routes  = (const int*)d_in[5];

    char* w = (char*)d_ws;
    unsigned short* xb_sw  = (unsigned short*)(w);                 // 4 MB
    unsigned short* wb1_sw = (unsigned short*)(w + (4u  << 20));   // 6 MB
    unsigned short* wb2_sw = (unsigned short*)(w + (10u << 20));   // 2 MB
    unsigned short* qbuf   = (unsigned short*)(w + (12u << 20));   // 4 MB bf16
    unsigned short* kbuf   = (unsigned short*)(w + (16u << 20));   // 4 MB bf16
    unsigned short* vbuf   = (unsigned short*)(w + (20u << 20));   // 4 MB bf16
    unsigned short* Vtg    = (unsigned short*)(w + (24u << 20));   // 4 MB
    unsigned short* attnsw = (unsigned short*)(w + (28u << 20));   // 4 MB
    unsigned int*   maskg  = (unsigned int*)(w + (32u << 20));     // 32 KB

    prep_kernel<<<3074, 256, 0, stream>>>(x, w_qkv, w_out, routes,
                                          xb_sw, wb1_sw, wb2_sw, maskg);

    gemm_qkv<<<dim3(THREE_D / 128, M_ROWS / 128), 256, 0, stream>>>(
        xb_sw, wb1_sw, b_qkv, qbuf, kbuf, vbuf);

    blend_v_kernel<<<256, 256, 0, stream>>>(vbuf, Vtg);

    attn_kernel<<<256, 512, 0, stream>>>(qbuf, kbuf, Vtg, maskg, attnsw);

    gemm_out<<<dim3(DD / 128, M_ROWS / 64), 256, 0, stream>>>(
        attnsw, wb2_sw, b_out, (float*)d_out);
}